// Round 1
// baseline (1204.132 us; speedup 1.0000x reference)
//
#include <hip/hip_runtime.h>

#define DH 128

// ---------- helpers ----------
__device__ __forceinline__ float wave_sum(float v) {
    #pragma unroll
    for (int o = 32; o > 0; o >>= 1) v += __shfl_xor(v, o, 64);
    return v;
}

// LayerNorm over 128 values held as (v0,v1) across a 64-lane wave.
__device__ __forceinline__ void ln_pair(float v0, float v1, float& o0, float& o1) {
    float m = wave_sum(v0 + v1) * (1.f / 128.f);
    float d0 = v0 - m, d1 = v1 - m;
    float var = wave_sum(d0 * d0 + d1 * d1) * (1.f / 128.f);
    float inv = rsqrtf(var + 1e-5f);
    o0 = d0 * inv; o1 = d1 * inv;
}

__device__ __forceinline__ float elu(float x) { return x > 0.f ? x : expm1f(x); }

// ---------- utility kernels ----------
__global__ void zero_k(float4* __restrict__ p, int n4) {
    int i = blockIdx.x * 256 + threadIdx.x;
    if (i < n4) p[i] = make_float4(0.f, 0.f, 0.f, 0.f);
}

__global__ void deg_count_k(const int* __restrict__ dst, int* __restrict__ deg, int E) {
    int e = blockIdx.x * 256 + threadIdx.x;
    if (e < E) atomicAdd(&deg[dst[e]], 1);
}

__global__ void dinv_k(const int* __restrict__ deg, float* __restrict__ dinv, int n) {
    int i = blockIdx.x * 256 + threadIdx.x;
    if (i < n) dinv[i] = rsqrtf((float)(deg[i] + 1));  // +1 self-loop
}

__global__ void norm_k(const int* __restrict__ src, const int* __restrict__ dst,
                       const float* __restrict__ dinv, float* __restrict__ nrm, int E) {
    int e = blockIdx.x * 256 + threadIdx.x;
    if (e < E) nrm[e] = dinv[src[e]] * dinv[dst[e]];
}

// ---------- GEMM: out[n,128] = x[n,DIN] @ W[DIN,128] (+bias), optionally dual ----------
template<int DIN, bool DUAL>
__global__ __launch_bounds__(256) void gemm_tile(
    const float* __restrict__ x,
    const float* __restrict__ Wa, const float* __restrict__ ba,
    const float* __restrict__ Wb, const float* __restrict__ bb,
    float* __restrict__ outa, float* __restrict__ outb, int n)
{
    __shared__ float xs[32 * DIN];
    const int tid = threadIdx.x;
    const long long base = (long long)blockIdx.x * 32 * DIN;
    const long long limit = (long long)n * DIN;
    #pragma unroll
    for (int i = tid * 4; i < 32 * DIN; i += 1024) {
        float4 v = make_float4(0.f, 0.f, 0.f, 0.f);
        if (base + i < limit) v = *(const float4*)(x + base + i);
        *(float4*)(xs + i) = v;
    }
    __syncthreads();
    const int c = tid & 127;          // output column
    const int rh = (tid >> 7) * 16;   // row half (0 or 16)
    float acca[16], accb[16];
    #pragma unroll
    for (int i = 0; i < 16; i++) { acca[i] = 0.f; accb[i] = 0.f; }
    for (int k = 0; k < DIN; k += 4) {
        float wa0 = Wa[(k + 0) * DH + c];
        float wa1 = Wa[(k + 1) * DH + c];
        float wa2 = Wa[(k + 2) * DH + c];
        float wa3 = Wa[(k + 3) * DH + c];
        float wb0 = 0.f, wb1 = 0.f, wb2 = 0.f, wb3 = 0.f;
        if constexpr (DUAL) {
            wb0 = Wb[(k + 0) * DH + c]; wb1 = Wb[(k + 1) * DH + c];
            wb2 = Wb[(k + 2) * DH + c]; wb3 = Wb[(k + 3) * DH + c];
        }
        #pragma unroll
        for (int i = 0; i < 16; i++) {
            float4 xv = *(const float4*)(xs + (rh + i) * DIN + k);
            acca[i] = fmaf(xv.x, wa0, acca[i]);
            acca[i] = fmaf(xv.y, wa1, acca[i]);
            acca[i] = fmaf(xv.z, wa2, acca[i]);
            acca[i] = fmaf(xv.w, wa3, acca[i]);
            if constexpr (DUAL) {
                accb[i] = fmaf(xv.x, wb0, accb[i]);
                accb[i] = fmaf(xv.y, wb1, accb[i]);
                accb[i] = fmaf(xv.z, wb2, accb[i]);
                accb[i] = fmaf(xv.w, wb3, accb[i]);
            }
        }
    }
    const float bav = ba ? ba[c] : 0.f;
    float bbv = 0.f;
    if constexpr (DUAL) bbv = bb ? bb[c] : 0.f;
    const int row0 = blockIdx.x * 32 + rh;
    #pragma unroll
    for (int i = 0; i < 16; i++) {
        int r = row0 + i;
        if (r < n) {
            outa[(long long)r * DH + c] = acca[i] + bav;
            if constexpr (DUAL) outb[(long long)r * DH + c] = accb[i] + bbv;
        }
    }
}

// ---------- edge scatter: agg[dst] += hw[src] * norm ----------
__global__ __launch_bounds__(256) void scatter_k(
    const float* __restrict__ hw, const int* __restrict__ src, const int* __restrict__ dst,
    const float* __restrict__ nrm, float* __restrict__ agg, int E)
{
    long long idx = (long long)blockIdx.x * 256 + threadIdx.x;
    if (idx >= (long long)E * DH) return;
    int e = (int)(idx >> 7);
    int d = (int)(idx & 127);
    float v = hw[(long long)src[e] * DH + d] * nrm[e];
    atomicAdd(&agg[(long long)dst[e] * DH + d], v);
}

// ---------- fuse layer 1: h = elu(LN(agg + dinv^2*hw + b1)) + LN(proj) ----------
__global__ __launch_bounds__(256) void fuse1_k(
    const float* __restrict__ agg, const float* __restrict__ hw, const float* __restrict__ proj,
    const float* __restrict__ dinv,
    const float* __restrict__ b1, const float* __restrict__ g1, const float* __restrict__ be1,
    const float* __restrict__ rg, const float* __restrict__ rbe,
    float* __restrict__ hout, int n)
{
    int row = blockIdx.x * 4 + (threadIdx.x >> 6);
    if (row >= n) return;
    int lane = threadIdx.x & 63;
    long long off = (long long)row * DH;
    float di = dinv[row], sl = di * di;
    float v0 = agg[off + lane]      + sl * hw[off + lane]      + b1[lane];
    float v1 = agg[off + lane + 64] + sl * hw[off + lane + 64] + b1[lane + 64];
    float o0, o1; ln_pair(v0, v1, o0, o1);
    float t0 = elu(o0 * g1[lane] + be1[lane]);
    float t1 = elu(o1 * g1[lane + 64] + be1[lane + 64]);
    float p0 = proj[off + lane], p1 = proj[off + lane + 64];
    float q0, q1; ln_pair(p0, p1, q0, q1);
    hout[off + lane]      = t0 + q0 * rg[lane] + rbe[lane];
    hout[off + lane + 64] = t1 + q1 * rg[lane + 64] + rbe[lane + 64];
}

// ---------- fuse layer 2: h2 = elu(LN(agg + dinv^2*hw + b2)) + hprev ----------
__global__ __launch_bounds__(256) void fuse2_k(
    const float* __restrict__ agg, const float* __restrict__ hw, const float* __restrict__ hprev,
    const float* __restrict__ dinv,
    const float* __restrict__ b2, const float* __restrict__ g2, const float* __restrict__ be2,
    float* __restrict__ h2, int n)
{
    int row = blockIdx.x * 4 + (threadIdx.x >> 6);
    if (row >= n) return;
    int lane = threadIdx.x & 63;
    long long off = (long long)row * DH;
    float di = dinv[row], sl = di * di;
    float v0 = agg[off + lane]      + sl * hw[off + lane]      + b2[lane];
    float v1 = agg[off + lane + 64] + sl * hw[off + lane + 64] + b2[lane + 64];
    float o0, o1; ln_pair(v0, v1, o0, o1);
    float t0 = elu(o0 * g2[lane] + be2[lane]);
    float t1 = elu(o1 * g2[lane + 64] + be2[lane + 64]);
    h2[off + lane]      = t0 + hprev[off + lane];
    h2[off + lane + 64] = t1 + hprev[off + lane + 64];
}

// ---------- LN + ELU on z ----------
__global__ __launch_bounds__(256) void ln_elu_k(
    const float* __restrict__ in, const float* __restrict__ g, const float* __restrict__ be,
    float* __restrict__ outp, int n)
{
    int row = blockIdx.x * 4 + (threadIdx.x >> 6);
    if (row >= n) return;
    int lane = threadIdx.x & 63;
    long long off = (long long)row * DH;
    float v0 = in[off + lane], v1 = in[off + lane + 64];
    float o0, o1; ln_pair(v0, v1, o0, o1);
    outp[off + lane]      = elu(o0 * g[lane] + be[lane]);
    outp[off + lane + 64] = elu(o1 * g[lane + 64] + be[lane + 64]);
}

// ---------- H = z @ mW2 + mb2, softmax over K=16; one wave per row ----------
__global__ __launch_bounds__(256) void final_k(
    const float* __restrict__ z, const float* __restrict__ mW2, const float* __restrict__ mb2,
    float* __restrict__ out, int n)
{
    int row = blockIdx.x * 4 + (threadIdx.x >> 6);
    if (row >= n) return;
    int lane = threadIdx.x & 63;
    int k = lane & 15, seg = lane >> 4;
    const float* zr = z + (long long)row * DH;
    float acc = 0.f;
    #pragma unroll
    for (int j = 0; j < 32; j++) {
        int c = seg * 32 + j;
        acc = fmaf(zr[c], mW2[c * 16 + k], acc);
    }
    acc += __shfl_xor(acc, 32, 64);
    acc += __shfl_xor(acc, 16, 64);
    float hk = acc + mb2[k];
    float mx = hk;
    #pragma unroll
    for (int o = 8; o > 0; o >>= 1) mx = fmaxf(mx, __shfl_xor(mx, o, 64));
    float e = expf(hk - mx);
    float s = e;
    #pragma unroll
    for (int o = 8; o > 0; o >>= 1) s += __shfl_xor(s, o, 64);
    if (lane < 16) out[(long long)row * 16 + k] = e / s;
}

// ---------- launcher ----------
extern "C" void kernel_launch(void* const* d_in, const int* in_sizes, int n_in,
                              void* d_out, int out_size, void* d_ws, size_t ws_size,
                              hipStream_t stream)
{
    const float* x   = (const float*)d_in[0];
    const int*   ei  = (const int*)d_in[1];
    const float* W1  = (const float*)d_in[2];
    const float* b1  = (const float*)d_in[3];
    const float* g1  = (const float*)d_in[4];
    const float* be1 = (const float*)d_in[5];
    const float* W2  = (const float*)d_in[6];
    const float* b2  = (const float*)d_in[7];
    const float* g2  = (const float*)d_in[8];
    const float* be2 = (const float*)d_in[9];
    const float* rW  = (const float*)d_in[10];
    const float* rb  = (const float*)d_in[11];
    const float* rg  = (const float*)d_in[12];
    const float* rbe = (const float*)d_in[13];
    const float* mW1 = (const float*)d_in[14];
    const float* mb1 = (const float*)d_in[15];
    const float* mg  = (const float*)d_in[16];
    const float* mbe = (const float*)d_in[17];
    const float* mW2 = (const float*)d_in[18];
    const float* mb2 = (const float*)d_in[19];
    float* out = (float*)d_out;

    const int n = in_sizes[0] / 384;
    const int E = in_sizes[1] / 2;
    const int* src = ei;
    const int* dst = ei + E;

    float* ws = (float*)d_ws;
    int*   deg  = (int*)ws;                      // n ints
    float* dinv = ws + n;                        // n
    float* nrm  = ws + 2 * (size_t)n;            // E
    float* hw1  = nrm + E;                       // n*128  (B2)
    float* proj = hw1 + (size_t)n * DH;          // n*128  (B3)
    float* agg  = proj + (size_t)n * DH;         // n*128  (B4) — reused both layers
    float* hbuf = agg + (size_t)n * DH;          // n*128  (B5)
    float* hw2  = proj;   // B3 reused after fuse1 consumed proj
    float* h2   = hw1;    // B2 reused after fuse1 consumed hw1
    float* zraw = hbuf;   // B5 reused after fuse2 consumed hbuf
    float* zbuf = agg;    // B4 reused after zGEMM

    int gE = (E + 255) / 256;
    int gN = (n + 255) / 256;
    int gGemm = (n + 31) / 32;
    int gScatter = (int)(((long long)E * DH + 255) / 256);
    int gRow4 = (n + 3) / 4;
    int gzAgg = (n * DH / 4 + 255) / 256;
    int gzDeg = ((n + 3) / 4 + 255) / 256;   // may spill into dinv; dinv rewritten later

    // degrees + norms
    zero_k<<<gzDeg, 256, 0, stream>>>((float4*)deg, (n + 3) / 4);
    zero_k<<<gzAgg, 256, 0, stream>>>((float4*)agg, n * DH / 4);
    deg_count_k<<<gE, 256, 0, stream>>>(dst, deg, E);
    dinv_k<<<gN, 256, 0, stream>>>(deg, dinv, n);
    norm_k<<<gE, 256, 0, stream>>>(src, dst, dinv, nrm, E);

    // layer 1
    gemm_tile<384, true><<<gGemm, 256, 0, stream>>>(x, W1, nullptr, rW, rb, hw1, proj, n);
    scatter_k<<<gScatter, 256, 0, stream>>>(hw1, src, dst, nrm, agg, E);
    fuse1_k<<<gRow4, 256, 0, stream>>>(agg, hw1, proj, dinv, b1, g1, be1, rg, rbe, hbuf, n);

    // layer 2
    gemm_tile<128, false><<<gGemm, 256, 0, stream>>>(hbuf, W2, nullptr, nullptr, nullptr, hw2, nullptr, n);
    zero_k<<<gzAgg, 256, 0, stream>>>((float4*)agg, n * DH / 4);
    scatter_k<<<gScatter, 256, 0, stream>>>(hw2, src, dst, nrm, agg, E);
    fuse2_k<<<gRow4, 256, 0, stream>>>(agg, hw2, hbuf, dinv, b2, g2, be2, h2, n);

    // MLP head + softmax
    gemm_tile<128, false><<<gGemm, 256, 0, stream>>>(h2, mW1, mb1, nullptr, nullptr, zraw, nullptr, n);
    ln_elu_k<<<gRow4, 256, 0, stream>>>(zraw, mg, mbe, zbuf, n);
    final_k<<<gRow4, 256, 0, stream>>>(zbuf, mW2, mb2, out, n);
}

// Round 2
// 709.732 us; speedup vs baseline: 1.6966x; 1.6966x over previous
//
#include <hip/hip_runtime.h>

#define DH 128

// ---------- helpers ----------
__device__ __forceinline__ float wave_sum(float v) {
    #pragma unroll
    for (int o = 32; o > 0; o >>= 1) v += __shfl_xor(v, o, 64);
    return v;
}

// LayerNorm over 128 values held as (v0,v1) across a 64-lane wave.
__device__ __forceinline__ void ln_pair(float v0, float v1, float& o0, float& o1) {
    float m = wave_sum(v0 + v1) * (1.f / 128.f);
    float d0 = v0 - m, d1 = v1 - m;
    float var = wave_sum(d0 * d0 + d1 * d1) * (1.f / 128.f);
    float inv = rsqrtf(var + 1e-5f);
    o0 = d0 * inv; o1 = d1 * inv;
}

__device__ __forceinline__ float elu(float x) { return x > 0.f ? x : expm1f(x); }

// ---------- utility kernels ----------
__global__ void zero_int_k(int* __restrict__ p, int n) {
    int i = blockIdx.x * 256 + threadIdx.x;
    if (i < n) p[i] = 0;
}

__global__ void deg_count_k(const int* __restrict__ dst, int* __restrict__ deg, int E) {
    int e = blockIdx.x * 256 + threadIdx.x;
    if (e < E) atomicAdd(&deg[dst[e]], 1);
}

__global__ void dinv_k(const int* __restrict__ deg, float* __restrict__ dinv, int n) {
    int i = blockIdx.x * 256 + threadIdx.x;
    if (i < n) dinv[i] = rsqrtf((float)(deg[i] + 1));  // +1 self-loop
}

// single-block chunked exclusive scan: rowptr[i] = sum_{j<i} deg[j]; cursor copy
__global__ __launch_bounds__(1024) void scan_k(const int* __restrict__ deg,
                                               int* __restrict__ rowptr,
                                               int* __restrict__ cursor, int n)
{
    __shared__ int wsum[16];
    __shared__ int carry;
    const int tid = threadIdx.x, lane = tid & 63, wid = tid >> 6;
    if (tid == 0) carry = 0;
    __syncthreads();
    for (int base = 0; base < n; base += 1024) {
        int i = base + tid;
        int v = (i < n) ? deg[i] : 0;
        int s = v;
        #pragma unroll
        for (int o = 1; o < 64; o <<= 1) {
            int t = __shfl_up(s, o, 64);
            if (lane >= o) s += t;
        }
        if (lane == 63) wsum[wid] = s;
        __syncthreads();
        if (tid < 16) {
            int ws = wsum[tid];
            #pragma unroll
            for (int o = 1; o < 16; o <<= 1) {
                int t = __shfl_up(ws, o, 64);
                if (tid >= o) ws += t;
            }
            wsum[tid] = ws;
        }
        __syncthreads();
        int excl = carry + (wid ? wsum[wid - 1] : 0) + s - v;
        if (i < n) { rowptr[i] = excl; cursor[i] = excl; }
        int tot = wsum[15];
        __syncthreads();
        if (tid == 0) carry += tot;
        __syncthreads();
    }
    if (threadIdx.x == 0) rowptr[n] = carry;
}

// place {src, norm} per edge into CSR slots of its dst row
__global__ void fill_k(const int* __restrict__ src, const int* __restrict__ dst,
                       const float* __restrict__ dinv, int* __restrict__ cursor,
                       int2* __restrict__ csr, int E)
{
    int e = blockIdx.x * 256 + threadIdx.x;
    if (e < E) {
        int s = src[e], d = dst[e];
        float w = dinv[s] * dinv[d];
        int p = atomicAdd(&cursor[d], 1);
        csr[p] = make_int2(s, __float_as_int(w));
    }
}

// ---------- GEMM: out[n,128] = x[n,DIN] @ W[DIN,128] (+bias), optionally dual ----------
template<int DIN, bool DUAL>
__global__ __launch_bounds__(256) void gemm_tile(
    const float* __restrict__ x,
    const float* __restrict__ Wa, const float* __restrict__ ba,
    const float* __restrict__ Wb, const float* __restrict__ bb,
    float* __restrict__ outa, float* __restrict__ outb, int n)
{
    __shared__ float xs[32 * DIN];
    const int tid = threadIdx.x;
    const long long base = (long long)blockIdx.x * 32 * DIN;
    const long long limit = (long long)n * DIN;
    #pragma unroll
    for (int i = tid * 4; i < 32 * DIN; i += 1024) {
        float4 v = make_float4(0.f, 0.f, 0.f, 0.f);
        if (base + i < limit) v = *(const float4*)(x + base + i);
        *(float4*)(xs + i) = v;
    }
    __syncthreads();
    const int c = tid & 127;          // output column
    const int rh = (tid >> 7) * 16;   // row half (0 or 16)
    float acca[16], accb[16];
    #pragma unroll
    for (int i = 0; i < 16; i++) { acca[i] = 0.f; accb[i] = 0.f; }
    for (int k = 0; k < DIN; k += 4) {
        float wa0 = Wa[(k + 0) * DH + c];
        float wa1 = Wa[(k + 1) * DH + c];
        float wa2 = Wa[(k + 2) * DH + c];
        float wa3 = Wa[(k + 3) * DH + c];
        float wb0 = 0.f, wb1 = 0.f, wb2 = 0.f, wb3 = 0.f;
        if constexpr (DUAL) {
            wb0 = Wb[(k + 0) * DH + c]; wb1 = Wb[(k + 1) * DH + c];
            wb2 = Wb[(k + 2) * DH + c]; wb3 = Wb[(k + 3) * DH + c];
        }
        #pragma unroll
        for (int i = 0; i < 16; i++) {
            float4 xv = *(const float4*)(xs + (rh + i) * DIN + k);
            acca[i] = fmaf(xv.x, wa0, acca[i]);
            acca[i] = fmaf(xv.y, wa1, acca[i]);
            acca[i] = fmaf(xv.z, wa2, acca[i]);
            acca[i] = fmaf(xv.w, wa3, acca[i]);
            if constexpr (DUAL) {
                accb[i] = fmaf(xv.x, wb0, accb[i]);
                accb[i] = fmaf(xv.y, wb1, accb[i]);
                accb[i] = fmaf(xv.z, wb2, accb[i]);
                accb[i] = fmaf(xv.w, wb3, accb[i]);
            }
        }
    }
    const float bav = ba ? ba[c] : 0.f;
    float bbv = 0.f;
    if constexpr (DUAL) bbv = bb ? bb[c] : 0.f;
    const int row0 = blockIdx.x * 32 + rh;
    #pragma unroll
    for (int i = 0; i < 16; i++) {
        int r = row0 + i;
        if (r < n) {
            outa[(long long)r * DH + c] = acca[i] + bav;
            if constexpr (DUAL) outb[(long long)r * DH + c] = accb[i] + bbv;
        }
    }
}

// ---------- CSR gather, one wave per row, fused epilogue ----------
// acc = sum_{e in row} nrm_e * hw[src_e]; then layer-specific epilogue.
__device__ __forceinline__ void gather_row(
    const float* __restrict__ hw, const int2* __restrict__ csr,
    int beg, int end, int lane, float& a0, float& a1)
{
    a0 = 0.f; a1 = 0.f;
    float b0 = 0.f, b1v = 0.f, c0 = 0.f, c1 = 0.f, d0 = 0.f, d1 = 0.f;
    int p = beg;
    for (; p + 3 < end; p += 4) {
        int2 e0 = csr[p], e1 = csr[p + 1], e2 = csr[p + 2], e3 = csr[p + 3];
        const float* h0 = hw + (long long)e0.x * DH;
        const float* h1 = hw + (long long)e1.x * DH;
        const float* h2 = hw + (long long)e2.x * DH;
        const float* h3 = hw + (long long)e3.x * DH;
        float w0 = __int_as_float(e0.y), w1 = __int_as_float(e1.y);
        float w2 = __int_as_float(e2.y), w3 = __int_as_float(e3.y);
        a0 = fmaf(w0, h0[lane], a0);       a1 = fmaf(w0, h0[lane + 64], a1);
        b0 = fmaf(w1, h1[lane], b0);       b1v = fmaf(w1, h1[lane + 64], b1v);
        c0 = fmaf(w2, h2[lane], c0);       c1 = fmaf(w2, h2[lane + 64], c1);
        d0 = fmaf(w3, h3[lane], d0);       d1 = fmaf(w3, h3[lane + 64], d1);
    }
    for (; p < end; ++p) {
        int2 e0 = csr[p];
        const float* h0 = hw + (long long)e0.x * DH;
        float w0 = __int_as_float(e0.y);
        a0 = fmaf(w0, h0[lane], a0);
        a1 = fmaf(w0, h0[lane + 64], a1);
    }
    a0 += b0 + c0 + d0;
    a1 += b1v + c1 + d1;
}

// layer 1: h = elu(LN(gather + dinv^2*hw + b1)) + LN(proj)
__global__ __launch_bounds__(256) void gfuse1_k(
    const float* __restrict__ hw, const float* __restrict__ proj,
    const int* __restrict__ rowptr, const int2* __restrict__ csr,
    const float* __restrict__ dinv,
    const float* __restrict__ b1, const float* __restrict__ g1, const float* __restrict__ be1,
    const float* __restrict__ rg, const float* __restrict__ rbe,
    float* __restrict__ hout, int n)
{
    int row = blockIdx.x * 4 + (threadIdx.x >> 6);
    if (row >= n) return;
    int lane = threadIdx.x & 63;
    float a0, a1;
    gather_row(hw, csr, rowptr[row], rowptr[row + 1], lane, a0, a1);
    long long off = (long long)row * DH;
    float di = dinv[row], sl = di * di;
    float v0 = a0 + sl * hw[off + lane]      + b1[lane];
    float v1 = a1 + sl * hw[off + lane + 64] + b1[lane + 64];
    float o0, o1; ln_pair(v0, v1, o0, o1);
    float t0 = elu(o0 * g1[lane] + be1[lane]);
    float t1 = elu(o1 * g1[lane + 64] + be1[lane + 64]);
    float p0 = proj[off + lane], p1 = proj[off + lane + 64];
    float q0, q1; ln_pair(p0, p1, q0, q1);
    hout[off + lane]      = t0 + q0 * rg[lane] + rbe[lane];
    hout[off + lane + 64] = t1 + q1 * rg[lane + 64] + rbe[lane + 64];
}

// layer 2: h2 = elu(LN(gather + dinv^2*hw + b2)) + hprev
__global__ __launch_bounds__(256) void gfuse2_k(
    const float* __restrict__ hw, const float* __restrict__ hprev,
    const int* __restrict__ rowptr, const int2* __restrict__ csr,
    const float* __restrict__ dinv,
    const float* __restrict__ b2, const float* __restrict__ g2, const float* __restrict__ be2,
    float* __restrict__ h2, int n)
{
    int row = blockIdx.x * 4 + (threadIdx.x >> 6);
    if (row >= n) return;
    int lane = threadIdx.x & 63;
    float a0, a1;
    gather_row(hw, csr, rowptr[row], rowptr[row + 1], lane, a0, a1);
    long long off = (long long)row * DH;
    float di = dinv[row], sl = di * di;
    float v0 = a0 + sl * hw[off + lane]      + b2[lane];
    float v1 = a1 + sl * hw[off + lane + 64] + b2[lane + 64];
    float o0, o1; ln_pair(v0, v1, o0, o1);
    float t0 = elu(o0 * g2[lane] + be2[lane]);
    float t1 = elu(o1 * g2[lane + 64] + be2[lane + 64]);
    h2[off + lane]      = t0 + hprev[off + lane];
    h2[off + lane + 64] = t1 + hprev[off + lane + 64];
}

// ---------- LN + ELU on z ----------
__global__ __launch_bounds__(256) void ln_elu_k(
    const float* __restrict__ in, const float* __restrict__ g, const float* __restrict__ be,
    float* __restrict__ outp, int n)
{
    int row = blockIdx.x * 4 + (threadIdx.x >> 6);
    if (row >= n) return;
    int lane = threadIdx.x & 63;
    long long off = (long long)row * DH;
    float v0 = in[off + lane], v1 = in[off + lane + 64];
    float o0, o1; ln_pair(v0, v1, o0, o1);
    outp[off + lane]      = elu(o0 * g[lane] + be[lane]);
    outp[off + lane + 64] = elu(o1 * g[lane + 64] + be[lane + 64]);
}

// ---------- H = z @ mW2 + mb2, softmax over K=16; one wave per row ----------
__global__ __launch_bounds__(256) void final_k(
    const float* __restrict__ z, const float* __restrict__ mW2, const float* __restrict__ mb2,
    float* __restrict__ out, int n)
{
    int row = blockIdx.x * 4 + (threadIdx.x >> 6);
    if (row >= n) return;
    int lane = threadIdx.x & 63;
    int k = lane & 15, seg = lane >> 4;
    const float* zr = z + (long long)row * DH;
    float acc = 0.f;
    #pragma unroll
    for (int j = 0; j < 32; j++) {
        int c = seg * 32 + j;
        acc = fmaf(zr[c], mW2[c * 16 + k], acc);
    }
    acc += __shfl_xor(acc, 32, 64);
    acc += __shfl_xor(acc, 16, 64);
    float hk = acc + mb2[k];
    float mx = hk;
    #pragma unroll
    for (int o = 8; o > 0; o >>= 1) mx = fmaxf(mx, __shfl_xor(mx, o, 64));
    float e = expf(hk - mx);
    float s = e;
    #pragma unroll
    for (int o = 8; o > 0; o >>= 1) s += __shfl_xor(s, o, 64);
    if (lane < 16) out[(long long)row * 16 + k] = e / s;
}

// ---------- launcher ----------
static inline size_t align16(size_t x) { return (x + 15) & ~(size_t)15; }

extern "C" void kernel_launch(void* const* d_in, const int* in_sizes, int n_in,
                              void* d_out, int out_size, void* d_ws, size_t ws_size,
                              hipStream_t stream)
{
    const float* x   = (const float*)d_in[0];
    const int*   ei  = (const int*)d_in[1];
    const float* W1  = (const float*)d_in[2];
    const float* b1  = (const float*)d_in[3];
    const float* g1  = (const float*)d_in[4];
    const float* be1 = (const float*)d_in[5];
    const float* W2  = (const float*)d_in[6];
    const float* b2  = (const float*)d_in[7];
    const float* g2  = (const float*)d_in[8];
    const float* be2 = (const float*)d_in[9];
    const float* rW  = (const float*)d_in[10];
    const float* rb  = (const float*)d_in[11];
    const float* rg  = (const float*)d_in[12];
    const float* rbe = (const float*)d_in[13];
    const float* mW1 = (const float*)d_in[14];
    const float* mb1 = (const float*)d_in[15];
    const float* mg  = (const float*)d_in[16];
    const float* mbe = (const float*)d_in[17];
    const float* mW2 = (const float*)d_in[18];
    const float* mb2 = (const float*)d_in[19];
    float* out = (float*)d_out;

    const int n = in_sizes[0] / 384;
    const int E = in_sizes[1] / 2;
    const int* src = ei;
    const int* dst = ei + E;

    char* w = (char*)d_ws;
    int* deg     = (int*)w;   w += align16((size_t)n * 4);
    int* rowptr  = (int*)w;   w += align16((size_t)(n + 1) * 4);
    int* cursor  = (int*)w;   w += align16((size_t)n * 4);
    float* dinv  = (float*)w; w += align16((size_t)n * 4);
    int2* csr    = (int2*)w;  w += align16((size_t)E * 8);
    float* hw1   = (float*)w; w += (size_t)n * DH * 4;
    float* proj  = (float*)w; w += (size_t)n * DH * 4;
    float* hbuf  = (float*)w; w += (size_t)n * DH * 4;
    float* hw2   = hw1;   // reused after gfuse1 consumed hw1
    float* h2    = proj;  // reused after gfuse1 consumed proj
    float* zraw  = hbuf;  // written by gemm(h2) while hbuf's hprev already consumed? NO:
    // gfuse2 reads hbuf (hprev) and writes h2(=proj). After gfuse2, hbuf is free.
    // zraw = hbuf (gemm reads h2=proj, writes hbuf). Then zbuf = hw1.
    float* zbuf  = hw1;

    int gE = (E + 255) / 256;
    int gN = (n + 255) / 256;
    int gGemm = (n + 31) / 32;
    int gRow4 = (n + 3) / 4;

    // CSR build
    zero_int_k<<<gN, 256, 0, stream>>>(deg, n);
    deg_count_k<<<gE, 256, 0, stream>>>(dst, deg, E);
    dinv_k<<<gN, 256, 0, stream>>>(deg, dinv, n);
    scan_k<<<1, 1024, 0, stream>>>(deg, rowptr, cursor, n);
    fill_k<<<gE, 256, 0, stream>>>(src, dst, dinv, cursor, csr, E);

    // layer 1
    gemm_tile<384, true><<<gGemm, 256, 0, stream>>>(x, W1, nullptr, rW, rb, hw1, proj, n);
    gfuse1_k<<<gRow4, 256, 0, stream>>>(hw1, proj, rowptr, csr, dinv,
                                        b1, g1, be1, rg, rbe, hbuf, n);

    // layer 2
    gemm_tile<128, false><<<gGemm, 256, 0, stream>>>(hbuf, W2, nullptr, nullptr, nullptr, hw2, nullptr, n);
    gfuse2_k<<<gRow4, 256, 0, stream>>>(hw2, hbuf, rowptr, csr, dinv,
                                        b2, g2, be2, h2, n);

    // MLP head + softmax
    gemm_tile<128, false><<<gGemm, 256, 0, stream>>>(h2, mW1, mb1, nullptr, nullptr, zraw, nullptr, n);
    ln_elu_k<<<gRow4, 256, 0, stream>>>(zraw, mg, mbe, zbuf, n);
    final_k<<<gRow4, 256, 0, stream>>>(zbuf, mW2, mb2, out, n);
}

// Round 3
// 561.027 us; speedup vs baseline: 2.1463x; 1.2651x over previous
//
#include <hip/hip_runtime.h>

#define DH 128

typedef __attribute__((ext_vector_type(8))) short short8;
typedef __attribute__((ext_vector_type(4))) float f32x4;

// ---------- helpers ----------
__device__ __forceinline__ float wave_sum(float v) {
    #pragma unroll
    for (int o = 32; o > 0; o >>= 1) v += __shfl_xor(v, o, 64);
    return v;
}

// LayerNorm over 128 values held as (v0,v1) across a 64-lane wave.
__device__ __forceinline__ void ln_pair(float v0, float v1, float& o0, float& o1) {
    float m = wave_sum(v0 + v1) * (1.f / 128.f);
    float d0 = v0 - m, d1 = v1 - m;
    float var = wave_sum(d0 * d0 + d1 * d1) * (1.f / 128.f);
    float inv = rsqrtf(var + 1e-5f);
    o0 = d0 * inv; o1 = d1 * inv;
}

__device__ __forceinline__ float elu(float x) { return x > 0.f ? x : expm1f(x); }

// fp32 -> bf16 round-to-nearest-even
__device__ __forceinline__ unsigned short f2bf(float f) {
    unsigned u = __float_as_uint(f);
    u += 0x7fffu + ((u >> 16) & 1u);
    return (unsigned short)(u >> 16);
}

// ---------- utility kernels ----------
__global__ void zero_int_k(int* __restrict__ p, int n) {
    int i = blockIdx.x * 256 + threadIdx.x;
    if (i < n) p[i] = 0;
}

__global__ void deg_count_k(const int* __restrict__ dst, int* __restrict__ deg, int E) {
    int e = blockIdx.x * 256 + threadIdx.x;
    if (e < E) atomicAdd(&deg[dst[e]], 1);
}

__global__ void dinv_k(const int* __restrict__ deg, float* __restrict__ dinv, int n) {
    int i = blockIdx.x * 256 + threadIdx.x;
    if (i < n) dinv[i] = rsqrtf((float)(deg[i] + 1));  // +1 self-loop
}

// single-block chunked exclusive scan: rowptr[i] = sum_{j<i} deg[j]; cursor copy
__global__ __launch_bounds__(1024) void scan_k(const int* __restrict__ deg,
                                               int* __restrict__ rowptr,
                                               int* __restrict__ cursor, int n)
{
    __shared__ int wsum[16];
    __shared__ int carry;
    const int tid = threadIdx.x, lane = tid & 63, wid = tid >> 6;
    if (tid == 0) carry = 0;
    __syncthreads();
    for (int base = 0; base < n; base += 1024) {
        int i = base + tid;
        int v = (i < n) ? deg[i] : 0;
        int s = v;
        #pragma unroll
        for (int o = 1; o < 64; o <<= 1) {
            int t = __shfl_up(s, o, 64);
            if (lane >= o) s += t;
        }
        if (lane == 63) wsum[wid] = s;
        __syncthreads();
        if (tid < 16) {
            int ws = wsum[tid];
            #pragma unroll
            for (int o = 1; o < 16; o <<= 1) {
                int t = __shfl_up(ws, o, 64);
                if (tid >= o) ws += t;
            }
            wsum[tid] = ws;
        }
        __syncthreads();
        int excl = carry + (wid ? wsum[wid - 1] : 0) + s - v;
        if (i < n) { rowptr[i] = excl; cursor[i] = excl; }
        int tot = wsum[15];
        __syncthreads();
        if (tid == 0) carry += tot;
        __syncthreads();
    }
    if (threadIdx.x == 0) rowptr[n] = carry;
}

// place {src, norm} per edge into CSR slots of its dst row
__global__ void fill_k(const int* __restrict__ src, const int* __restrict__ dst,
                       const float* __restrict__ dinv, int* __restrict__ cursor,
                       int2* __restrict__ csr, int E)
{
    int e = blockIdx.x * 256 + threadIdx.x;
    if (e < E) {
        int s = src[e], d = dst[e];
        float w = dinv[s] * dinv[d];
        int p = atomicAdd(&cursor[d], 1);
        csr[p] = make_int2(s, __float_as_int(w));
    }
}

// repack W [K x 128] fp32 -> Wp[kb][n][32] bf16 (fragment-ordered panels)
__global__ void repack_w_k(const float* __restrict__ W, unsigned short* __restrict__ Wp, int K) {
    int idx = blockIdx.x * 256 + threadIdx.x;
    if (idx >= K * DH) return;
    int kb  = idx / (DH * 32);
    int rem = idx - kb * (DH * 32);
    int nn  = rem >> 5;
    int ki  = rem & 31;
    Wp[idx] = f2bf(W[(kb * 32 + ki) * DH + nn]);
}

// ---------- MFMA GEMM: out[n,128] = A[n,K] @ W[K,128] (+bias), optionally dual ----------
// Block: 128 rows x 128 cols, 4 waves (2x2), each wave 64x64 via 4x4 of 16x16x32 bf16 MFMA.
// A fp32 in global, converted to bf16 during LDS staging. B pre-repacked bf16 panels.
template<int K, bool DUAL>
__global__ __launch_bounds__(256) void mfma_gemm(
    const float* __restrict__ A,
    const unsigned short* __restrict__ Bp1, const float* __restrict__ ba,
    const unsigned short* __restrict__ Bp2, const float* __restrict__ bb,
    float* __restrict__ outa, float* __restrict__ outb, int n)
{
    constexpr int LDA = 40;                      // padded LDS row (ushort units): 2-way bank alias only
    constexpr int NBUF = DUAL ? 3 : 2;
    __shared__ unsigned short smem[NBUF * 128 * LDA];
    unsigned short* As  = smem;
    unsigned short* Bs1 = smem + 128 * LDA;
    unsigned short* Bs2 = smem + 2 * 128 * LDA;  // only touched if DUAL

    const int tid  = threadIdx.x;
    const int wid  = tid >> 6, lane = tid & 63;
    const int wr   = wid >> 1, wc = wid & 1;
    const int m16  = lane & 15, q = lane >> 4;
    const long long rowbase = (long long)blockIdx.x * 128;

    f32x4 acc1[4][4], acc2[4][4];
    const f32x4 zero = {0.f, 0.f, 0.f, 0.f};
    #pragma unroll
    for (int i = 0; i < 4; i++)
        #pragma unroll
        for (int j = 0; j < 4; j++) { acc1[i][j] = zero; if constexpr (DUAL) acc2[i][j] = zero; }

    for (int kb = 0; kb < K / 32; ++kb) {
        // stage A: 128 rows x 32 k, fp32 -> bf16 (1024 16B-fp32 chunks, 4/thread)
        #pragma unroll
        for (int h = 0; h < 4; ++h) {
            int c = tid + h * 256;
            int r = c >> 3, kq = c & 7;
            long long gr = rowbase + r; if (gr >= n) gr = n - 1;
            float4 v = *(const float4*)(A + gr * K + kb * 32 + kq * 4);
            ushort4 o = make_ushort4(f2bf(v.x), f2bf(v.y), f2bf(v.z), f2bf(v.w));
            *(ushort4*)(As + r * LDA + kq * 4) = o;
        }
        // stage B panels (already bf16, fragment-ordered: [n][32k] contiguous)
        const unsigned short* bsrc1 = Bp1 + (long long)kb * (128 * 32);
        #pragma unroll
        for (int h = 0; h < 2; ++h) {
            int c = tid + h * 256;
            int r = c >> 2, kq = c & 3;
            short8 w1 = *(const short8*)(bsrc1 + c * 8);
            *(short8*)(Bs1 + r * LDA + kq * 8) = w1;
            if constexpr (DUAL) {
                short8 w2 = *(const short8*)(Bp2 + (long long)kb * (128 * 32) + c * 8);
                *(short8*)(Bs2 + r * LDA + kq * 8) = w2;
            }
        }
        __syncthreads();

        short8 af[4], bfr1[4], bfr2[4];
        #pragma unroll
        for (int mi = 0; mi < 4; ++mi)
            af[mi] = *(const short8*)(As + (wr * 64 + mi * 16 + m16) * LDA + q * 8);
        #pragma unroll
        for (int nj = 0; nj < 4; ++nj) {
            bfr1[nj] = *(const short8*)(Bs1 + (wc * 64 + nj * 16 + m16) * LDA + q * 8);
            if constexpr (DUAL)
                bfr2[nj] = *(const short8*)(Bs2 + (wc * 64 + nj * 16 + m16) * LDA + q * 8);
        }
        #pragma unroll
        for (int mi = 0; mi < 4; ++mi)
            #pragma unroll
            for (int nj = 0; nj < 4; ++nj) {
                acc1[mi][nj] = __builtin_amdgcn_mfma_f32_16x16x32_bf16(af[mi], bfr1[nj], acc1[mi][nj], 0, 0, 0);
                if constexpr (DUAL)
                    acc2[mi][nj] = __builtin_amdgcn_mfma_f32_16x16x32_bf16(af[mi], bfr2[nj], acc2[mi][nj], 0, 0, 0);
            }
        __syncthreads();
    }

    // epilogue: C/D layout col=lane&15, row=(lane>>4)*4+reg
    #pragma unroll
    for (int nj = 0; nj < 4; ++nj) {
        int col = wc * 64 + nj * 16 + m16;
        float bav = ba ? ba[col] : 0.f;
        float bbv = 0.f;
        if constexpr (DUAL) bbv = bb ? bb[col] : 0.f;
        #pragma unroll
        for (int mi = 0; mi < 4; ++mi) {
            long long row0 = rowbase + wr * 64 + mi * 16 + q * 4;
            #pragma unroll
            for (int r = 0; r < 4; ++r) {
                long long rr = row0 + r;
                if (rr < n) {
                    outa[rr * DH + col] = acc1[mi][nj][r] + bav;
                    if constexpr (DUAL) outb[rr * DH + col] = acc2[mi][nj][r] + bbv;
                }
            }
        }
    }
}

// ---------- CSR gather, one wave per row, fused epilogue ----------
__device__ __forceinline__ void gather_row(
    const float* __restrict__ hw, const int2* __restrict__ csr,
    int beg, int end, int lane, float& a0, float& a1)
{
    a0 = 0.f; a1 = 0.f;
    float b0 = 0.f, b1v = 0.f, c0 = 0.f, c1 = 0.f, d0 = 0.f, d1 = 0.f;
    int p = beg;
    for (; p + 3 < end; p += 4) {
        int2 e0 = csr[p], e1 = csr[p + 1], e2 = csr[p + 2], e3 = csr[p + 3];
        const float* h0 = hw + (long long)e0.x * DH;
        const float* h1 = hw + (long long)e1.x * DH;
        const float* h2 = hw + (long long)e2.x * DH;
        const float* h3 = hw + (long long)e3.x * DH;
        float w0 = __int_as_float(e0.y), w1 = __int_as_float(e1.y);
        float w2 = __int_as_float(e2.y), w3 = __int_as_float(e3.y);
        a0 = fmaf(w0, h0[lane], a0);       a1 = fmaf(w0, h0[lane + 64], a1);
        b0 = fmaf(w1, h1[lane], b0);       b1v = fmaf(w1, h1[lane + 64], b1v);
        c0 = fmaf(w2, h2[lane], c0);       c1 = fmaf(w2, h2[lane + 64], c1);
        d0 = fmaf(w3, h3[lane], d0);       d1 = fmaf(w3, h3[lane + 64], d1);
    }
    for (; p < end; ++p) {
        int2 e0 = csr[p];
        const float* h0 = hw + (long long)e0.x * DH;
        float w0 = __int_as_float(e0.y);
        a0 = fmaf(w0, h0[lane], a0);
        a1 = fmaf(w0, h0[lane + 64], a1);
    }
    a0 += b0 + c0 + d0;
    a1 += b1v + c1 + d1;
}

// layer 1: h = elu(LN(gather + dinv^2*hw + b1)) + LN(proj)
__global__ __launch_bounds__(256) void gfuse1_k(
    const float* __restrict__ hw, const float* __restrict__ proj,
    const int* __restrict__ rowptr, const int2* __restrict__ csr,
    const float* __restrict__ dinv,
    const float* __restrict__ b1, const float* __restrict__ g1, const float* __restrict__ be1,
    const float* __restrict__ rg, const float* __restrict__ rbe,
    float* __restrict__ hout, int n)
{
    int row = blockIdx.x * 4 + (threadIdx.x >> 6);
    if (row >= n) return;
    int lane = threadIdx.x & 63;
    float a0, a1;
    gather_row(hw, csr, rowptr[row], rowptr[row + 1], lane, a0, a1);
    long long off = (long long)row * DH;
    float di = dinv[row], sl = di * di;
    float v0 = a0 + sl * hw[off + lane]      + b1[lane];
    float v1 = a1 + sl * hw[off + lane + 64] + b1[lane + 64];
    float o0, o1; ln_pair(v0, v1, o0, o1);
    float t0 = elu(o0 * g1[lane] + be1[lane]);
    float t1 = elu(o1 * g1[lane + 64] + be1[lane + 64]);
    float p0 = proj[off + lane], p1 = proj[off + lane + 64];
    float q0, q1; ln_pair(p0, p1, q0, q1);
    hout[off + lane]      = t0 + q0 * rg[lane] + rbe[lane];
    hout[off + lane + 64] = t1 + q1 * rg[lane + 64] + rbe[lane + 64];
}

// layer 2: h2 = elu(LN(gather + dinv^2*hw + b2)) + hprev
__global__ __launch_bounds__(256) void gfuse2_k(
    const float* __restrict__ hw, const float* __restrict__ hprev,
    const int* __restrict__ rowptr, const int2* __restrict__ csr,
    const float* __restrict__ dinv,
    const float* __restrict__ b2, const float* __restrict__ g2, const float* __restrict__ be2,
    float* __restrict__ h2, int n)
{
    int row = blockIdx.x * 4 + (threadIdx.x >> 6);
    if (row >= n) return;
    int lane = threadIdx.x & 63;
    float a0, a1;
    gather_row(hw, csr, rowptr[row], rowptr[row + 1], lane, a0, a1);
    long long off = (long long)row * DH;
    float di = dinv[row], sl = di * di;
    float v0 = a0 + sl * hw[off + lane]      + b2[lane];
    float v1 = a1 + sl * hw[off + lane + 64] + b2[lane + 64];
    float o0, o1; ln_pair(v0, v1, o0, o1);
    float t0 = elu(o0 * g2[lane] + be2[lane]);
    float t1 = elu(o1 * g2[lane + 64] + be2[lane + 64]);
    h2[off + lane]      = t0 + hprev[off + lane];
    h2[off + lane + 64] = t1 + hprev[off + lane + 64];
}

// ---------- LN + ELU on z ----------
__global__ __launch_bounds__(256) void ln_elu_k(
    const float* __restrict__ in, const float* __restrict__ g, const float* __restrict__ be,
    float* __restrict__ outp, int n)
{
    int row = blockIdx.x * 4 + (threadIdx.x >> 6);
    if (row >= n) return;
    int lane = threadIdx.x & 63;
    long long off = (long long)row * DH;
    float v0 = in[off + lane], v1 = in[off + lane + 64];
    float o0, o1; ln_pair(v0, v1, o0, o1);
    outp[off + lane]      = elu(o0 * g[lane] + be[lane]);
    outp[off + lane + 64] = elu(o1 * g[lane + 64] + be[lane + 64]);
}

// ---------- H = z @ mW2 + mb2, softmax over K=16; one wave per row ----------
__global__ __launch_bounds__(256) void final_k(
    const float* __restrict__ z, const float* __restrict__ mW2, const float* __restrict__ mb2,
    float* __restrict__ out, int n)
{
    int row = blockIdx.x * 4 + (threadIdx.x >> 6);
    if (row >= n) return;
    int lane = threadIdx.x & 63;
    int k = lane & 15, seg = lane >> 4;
    const float* zr = z + (long long)row * DH;
    float acc = 0.f;
    #pragma unroll
    for (int j = 0; j < 32; j++) {
        int c = seg * 32 + j;
        acc = fmaf(zr[c], mW2[c * 16 + k], acc);
    }
    acc += __shfl_xor(acc, 32, 64);
    acc += __shfl_xor(acc, 16, 64);
    float hk = acc + mb2[k];
    float mx = hk;
    #pragma unroll
    for (int o = 8; o > 0; o >>= 1) mx = fmaxf(mx, __shfl_xor(mx, o, 64));
    float e = expf(hk - mx);
    float s = e;
    #pragma unroll
    for (int o = 8; o > 0; o >>= 1) s += __shfl_xor(s, o, 64);
    if (lane < 16) out[(long long)row * 16 + k] = e / s;
}

// ---------- launcher ----------
static inline size_t align16(size_t x) { return (x + 15) & ~(size_t)15; }

extern "C" void kernel_launch(void* const* d_in, const int* in_sizes, int n_in,
                              void* d_out, int out_size, void* d_ws, size_t ws_size,
                              hipStream_t stream)
{
    const float* x   = (const float*)d_in[0];
    const int*   ei  = (const int*)d_in[1];
    const float* W1  = (const float*)d_in[2];
    const float* b1  = (const float*)d_in[3];
    const float* g1  = (const float*)d_in[4];
    const float* be1 = (const float*)d_in[5];
    const float* W2  = (const float*)d_in[6];
    const float* b2  = (const float*)d_in[7];
    const float* g2  = (const float*)d_in[8];
    const float* be2 = (const float*)d_in[9];
    const float* rW  = (const float*)d_in[10];
    const float* rb  = (const float*)d_in[11];
    const float* rg  = (const float*)d_in[12];
    const float* rbe = (const float*)d_in[13];
    const float* mW1 = (const float*)d_in[14];
    const float* mb1 = (const float*)d_in[15];
    const float* mg  = (const float*)d_in[16];
    const float* mbe = (const float*)d_in[17];
    const float* mW2 = (const float*)d_in[18];
    const float* mb2 = (const float*)d_in[19];
    float* out = (float*)d_out;

    const int n = in_sizes[0] / 384;
    const int E = in_sizes[1] / 2;
    const int* src = ei;
    const int* dst = ei + E;

    char* w = (char*)d_ws;
    int* deg     = (int*)w;   w += align16((size_t)n * 4);
    int* rowptr  = (int*)w;   w += align16((size_t)(n + 1) * 4);
    int* cursor  = (int*)w;   w += align16((size_t)n * 4);
    float* dinv  = (float*)w; w += align16((size_t)n * 4);
    int2* csr    = (int2*)w;  w += align16((size_t)E * 8);
    float* hw1   = (float*)w; w += (size_t)n * DH * 4;
    float* proj  = (float*)w; w += (size_t)n * DH * 4;
    float* hbuf  = (float*)w; w += (size_t)n * DH * 4;
    unsigned short* Wp1 = (unsigned short*)w; w += align16((size_t)384 * DH * 2);
    unsigned short* Wpr = (unsigned short*)w; w += align16((size_t)384 * DH * 2);
    unsigned short* Wp2 = (unsigned short*)w; w += align16((size_t)128 * DH * 2);
    unsigned short* WpM = (unsigned short*)w; w += align16((size_t)128 * DH * 2);
    float* hw2   = hw1;   // reused after gfuse1 consumed hw1
    float* h2    = proj;  // reused after gfuse1 consumed proj
    float* zraw  = hbuf;  // reused after gfuse2 consumed hbuf
    float* zbuf  = hw1;

    int gE = (E + 255) / 256;
    int gN = (n + 255) / 256;
    int gG = (n + 127) / 128;
    int gRow4 = (n + 3) / 4;

    // CSR build
    zero_int_k<<<gN, 256, 0, stream>>>(deg, n);
    deg_count_k<<<gE, 256, 0, stream>>>(dst, deg, E);
    dinv_k<<<gN, 256, 0, stream>>>(deg, dinv, n);
    scan_k<<<1, 1024, 0, stream>>>(deg, rowptr, cursor, n);
    fill_k<<<gE, 256, 0, stream>>>(src, dst, dinv, cursor, csr, E);

    // weight repack to bf16 fragment panels
    repack_w_k<<<(384 * DH + 255) / 256, 256, 0, stream>>>(W1, Wp1, 384);
    repack_w_k<<<(384 * DH + 255) / 256, 256, 0, stream>>>(rW, Wpr, 384);
    repack_w_k<<<(128 * DH + 255) / 256, 256, 0, stream>>>(W2, Wp2, 128);
    repack_w_k<<<(128 * DH + 255) / 256, 256, 0, stream>>>(mW1, WpM, 128);

    // layer 1
    mfma_gemm<384, true><<<gG, 256, 0, stream>>>(x, Wp1, nullptr, Wpr, rb, hw1, proj, n);
    gfuse1_k<<<gRow4, 256, 0, stream>>>(hw1, proj, rowptr, csr, dinv,
                                        b1, g1, be1, rg, rbe, hbuf, n);

    // layer 2
    mfma_gemm<128, false><<<gG, 256, 0, stream>>>(hbuf, Wp2, nullptr, nullptr, nullptr, hw2, nullptr, n);
    gfuse2_k<<<gRow4, 256, 0, stream>>>(hw2, hbuf, rowptr, csr, dinv,
                                        b2, g2, be2, h2, n);

    // MLP head + softmax
    mfma_gemm<128, false><<<gG, 256, 0, stream>>>(h2, WpM, mb1, nullptr, nullptr, zraw, nullptr, n);
    ln_elu_k<<<gRow4, 256, 0, stream>>>(zraw, mg, mbe, zbuf, n);
    final_k<<<gRow4, 256, 0, stream>>>(zbuf, mW2, mb2, out, n);
}

// Round 4
// 478.775 us; speedup vs baseline: 2.5150x; 1.1718x over previous
//
#include <hip/hip_runtime.h>

#define DH 128

typedef __attribute__((ext_vector_type(8))) short short8;
typedef __attribute__((ext_vector_type(4))) float f32x4;

// ---------- helpers ----------
__device__ __forceinline__ float wave_sum(float v) {
    #pragma unroll
    for (int o = 32; o > 0; o >>= 1) v += __shfl_xor(v, o, 64);
    return v;
}

__device__ __forceinline__ void ln_pair(float v0, float v1, float& o0, float& o1) {
    float m = wave_sum(v0 + v1) * (1.f / 128.f);
    float d0 = v0 - m, d1 = v1 - m;
    float var = wave_sum(d0 * d0 + d1 * d1) * (1.f / 128.f);
    float inv = rsqrtf(var + 1e-5f);
    o0 = d0 * inv; o1 = d1 * inv;
}

__device__ __forceinline__ float elu(float x) { return x > 0.f ? x : expm1f(x); }

// fp32 -> bf16 round-to-nearest-even
__device__ __forceinline__ unsigned short f2bf(float f) {
    unsigned u = __float_as_uint(f);
    u += 0x7fffu + ((u >> 16) & 1u);
    return (unsigned short)(u >> 16);
}
// packed bf16 pair <-> float
__device__ __forceinline__ float bfl(unsigned u) { return __uint_as_float(u << 16); }
__device__ __forceinline__ float bfh(unsigned u) { return __uint_as_float(u & 0xffff0000u); }
__device__ __forceinline__ unsigned pack_bf2(float a, float b) {
    return (unsigned)f2bf(a) | ((unsigned)f2bf(b) << 16);
}

// ---------- utility kernels ----------
__global__ void zero_int_k(int* __restrict__ p, int n) {
    int i = blockIdx.x * 256 + threadIdx.x;
    if (i < n) p[i] = 0;
}

__global__ void deg_count_k(const int* __restrict__ dst, int* __restrict__ deg, int E) {
    int e = blockIdx.x * 256 + threadIdx.x;
    if (e < E) atomicAdd(&deg[dst[e]], 1);
}

__global__ void dinv_k(const int* __restrict__ deg, float* __restrict__ dinv, int n) {
    int i = blockIdx.x * 256 + threadIdx.x;
    if (i < n) dinv[i] = rsqrtf((float)(deg[i] + 1));  // +1 self-loop
}

// single-block chunked exclusive scan
__global__ __launch_bounds__(1024) void scan_k(const int* __restrict__ deg,
                                               int* __restrict__ rowptr,
                                               int* __restrict__ cursor, int n)
{
    __shared__ int wsum[16];
    __shared__ int carry;
    const int tid = threadIdx.x, lane = tid & 63, wid = tid >> 6;
    if (tid == 0) carry = 0;
    __syncthreads();
    for (int base = 0; base < n; base += 1024) {
        int i = base + tid;
        int v = (i < n) ? deg[i] : 0;
        int s = v;
        #pragma unroll
        for (int o = 1; o < 64; o <<= 1) {
            int t = __shfl_up(s, o, 64);
            if (lane >= o) s += t;
        }
        if (lane == 63) wsum[wid] = s;
        __syncthreads();
        if (tid < 16) {
            int ws = wsum[tid];
            #pragma unroll
            for (int o = 1; o < 16; o <<= 1) {
                int t = __shfl_up(ws, o, 64);
                if (tid >= o) ws += t;
            }
            wsum[tid] = ws;
        }
        __syncthreads();
        int excl = carry + (wid ? wsum[wid - 1] : 0) + s - v;
        if (i < n) { rowptr[i] = excl; cursor[i] = excl; }
        int tot = wsum[15];
        __syncthreads();
        if (tid == 0) carry += tot;
        __syncthreads();
    }
    if (threadIdx.x == 0) rowptr[n] = carry;
}

__global__ void fill_k(const int* __restrict__ src, const int* __restrict__ dst,
                       const float* __restrict__ dinv, int* __restrict__ cursor,
                       int2* __restrict__ csr, int E)
{
    int e = blockIdx.x * 256 + threadIdx.x;
    if (e < E) {
        int s = src[e], d = dst[e];
        float w = dinv[s] * dinv[d];
        int p = atomicAdd(&cursor[d], 1);
        csr[p] = make_int2(s, __float_as_int(w));
    }
}

// repack W [K x 128] fp32 -> Wp[kb][n][32] bf16 (fragment-ordered panels)
__global__ void repack_w_k(const float* __restrict__ W, unsigned short* __restrict__ Wp, int K) {
    int idx = blockIdx.x * 256 + threadIdx.x;
    if (idx >= K * DH) return;
    int kb  = idx / (DH * 32);
    int rem = idx - kb * (DH * 32);
    int nn  = rem >> 5;
    int ki  = rem & 31;
    Wp[idx] = f2bf(W[(kb * 32 + ki) * DH + nn]);
}

// ---------- MFMA GEMM: out[n,128] = A[n,K] @ W[K,128] (+bias), bf16 out ----------
// Block: 64 rows x 128 cols, 4 waves (2x2), wave = 32x64 via 2x4 of 16x16x32 bf16 MFMA.
template<int K, bool DUAL, bool AF32>
__global__ __launch_bounds__(256) void mfma_gemm(
    const void* __restrict__ Av,
    const unsigned short* __restrict__ Bp1, const float* __restrict__ ba,
    const unsigned short* __restrict__ Bp2, const float* __restrict__ bb,
    unsigned short* __restrict__ outa, unsigned short* __restrict__ outb, int n)
{
    constexpr int LDA = 40;  // padded LDS row (ushort): 80 B stride, 2-way alias only
    __shared__ unsigned short smem[64 * LDA + (DUAL ? 2 : 1) * 128 * LDA];
    unsigned short* As  = smem;
    unsigned short* Bs1 = smem + 64 * LDA;
    unsigned short* Bs2 = smem + 64 * LDA + 128 * LDA;

    const int tid  = threadIdx.x;
    const int wid  = tid >> 6, lane = tid & 63;
    const int wr   = wid >> 1, wc = wid & 1;
    const int m16  = lane & 15, q = lane >> 4;
    const long long rowbase = (long long)blockIdx.x * 64;

    f32x4 acc1[2][4], acc2[2][4];
    const f32x4 zero = {0.f, 0.f, 0.f, 0.f};
    #pragma unroll
    for (int i = 0; i < 2; i++)
        #pragma unroll
        for (int j = 0; j < 4; j++) { acc1[i][j] = zero; if constexpr (DUAL) acc2[i][j] = zero; }

    // per-thread staging coords (64x32 A-tile = 256 chunks of 8)
    const int ar = tid >> 2, akq = tid & 3;
    long long gr = rowbase + ar; if (gr >= n) gr = n - 1;

    for (int kb = 0; kb < K / 32; ++kb) {
        // stage A (fp32->bf16 convert, or bf16 copy)
        if constexpr (AF32) {
            const float* A = (const float*)Av;
            const float* ap = A + gr * K + kb * 32 + akq * 8;
            float4 v0 = *(const float4*)(ap);
            float4 v1 = *(const float4*)(ap + 4);
            short8 o;
            o[0] = (short)f2bf(v0.x); o[1] = (short)f2bf(v0.y);
            o[2] = (short)f2bf(v0.z); o[3] = (short)f2bf(v0.w);
            o[4] = (short)f2bf(v1.x); o[5] = (short)f2bf(v1.y);
            o[6] = (short)f2bf(v1.z); o[7] = (short)f2bf(v1.w);
            *(short8*)(As + ar * LDA + akq * 8) = o;
        } else {
            const unsigned short* A = (const unsigned short*)Av;
            short8 o = *(const short8*)(A + gr * K + kb * 32 + akq * 8);
            *(short8*)(As + ar * LDA + akq * 8) = o;
        }
        // stage B panels (bf16 fragment-ordered [n][32])
        #pragma unroll
        for (int h = 0; h < 2; ++h) {
            int cb = tid + h * 256;
            int rb_ = cb >> 2, kqb = cb & 3;
            short8 w1 = *(const short8*)(Bp1 + (long long)kb * 4096 + cb * 8);
            *(short8*)(Bs1 + rb_ * LDA + kqb * 8) = w1;
            if constexpr (DUAL) {
                short8 w2 = *(const short8*)(Bp2 + (long long)kb * 4096 + cb * 8);
                *(short8*)(Bs2 + rb_ * LDA + kqb * 8) = w2;
            }
        }
        __syncthreads();

        short8 af[2], bfr1[4], bfr2[4];
        #pragma unroll
        for (int mi = 0; mi < 2; ++mi)
            af[mi] = *(const short8*)(As + (wr * 32 + mi * 16 + m16) * LDA + q * 8);
        #pragma unroll
        for (int nj = 0; nj < 4; ++nj) {
            bfr1[nj] = *(const short8*)(Bs1 + (wc * 64 + nj * 16 + m16) * LDA + q * 8);
            if constexpr (DUAL)
                bfr2[nj] = *(const short8*)(Bs2 + (wc * 64 + nj * 16 + m16) * LDA + q * 8);
        }
        #pragma unroll
        for (int mi = 0; mi < 2; ++mi)
            #pragma unroll
            for (int nj = 0; nj < 4; ++nj) {
                acc1[mi][nj] = __builtin_amdgcn_mfma_f32_16x16x32_bf16(af[mi], bfr1[nj], acc1[mi][nj], 0, 0, 0);
                if constexpr (DUAL)
                    acc2[mi][nj] = __builtin_amdgcn_mfma_f32_16x16x32_bf16(af[mi], bfr2[nj], acc2[mi][nj], 0, 0, 0);
            }
        __syncthreads();
    }

    // epilogue: C/D layout col=lane&15, row=(lane>>4)*4+reg ; write bf16
    #pragma unroll
    for (int nj = 0; nj < 4; ++nj) {
        int col = wc * 64 + nj * 16 + m16;
        float bav = ba ? ba[col] : 0.f;
        float bbv = 0.f;
        if constexpr (DUAL) bbv = bb ? bb[col] : 0.f;
        #pragma unroll
        for (int mi = 0; mi < 2; ++mi) {
            long long row0 = rowbase + wr * 32 + mi * 16 + q * 4;
            #pragma unroll
            for (int r = 0; r < 4; ++r) {
                long long rr = row0 + r;
                if (rr < n) {
                    outa[rr * DH + col] = f2bf(acc1[mi][nj][r] + bav);
                    if constexpr (DUAL) outb[rr * DH + col] = f2bf(acc2[mi][nj][r] + bbv);
                }
            }
        }
    }
}

// ---------- CSR gather (bf16 rows), one wave per row ----------
// lane holds cols (2*lane, 2*lane+1)
__device__ __forceinline__ void gather_row(
    const unsigned* __restrict__ hw, const int2* __restrict__ csr,
    int beg, int end, int lane, float& a0, float& a1)
{
    a0 = 0.f; a1 = 0.f;
    float b0 = 0.f, b1v = 0.f, c0 = 0.f, c1 = 0.f, d0 = 0.f, d1 = 0.f;
    int p = beg;
    for (; p + 3 < end; p += 4) {
        int2 e0 = csr[p], e1 = csr[p + 1], e2 = csr[p + 2], e3 = csr[p + 3];
        unsigned u0 = hw[(long long)e0.x * 64 + lane];
        unsigned u1 = hw[(long long)e1.x * 64 + lane];
        unsigned u2 = hw[(long long)e2.x * 64 + lane];
        unsigned u3 = hw[(long long)e3.x * 64 + lane];
        float w0 = __int_as_float(e0.y), w1 = __int_as_float(e1.y);
        float w2 = __int_as_float(e2.y), w3 = __int_as_float(e3.y);
        a0 = fmaf(w0, bfl(u0), a0);   a1 = fmaf(w0, bfh(u0), a1);
        b0 = fmaf(w1, bfl(u1), b0);   b1v = fmaf(w1, bfh(u1), b1v);
        c0 = fmaf(w2, bfl(u2), c0);   c1 = fmaf(w2, bfh(u2), c1);
        d0 = fmaf(w3, bfl(u3), d0);   d1 = fmaf(w3, bfh(u3), d1);
    }
    for (; p < end; ++p) {
        int2 e0 = csr[p];
        unsigned u0 = hw[(long long)e0.x * 64 + lane];
        float w0 = __int_as_float(e0.y);
        a0 = fmaf(w0, bfl(u0), a0);
        a1 = fmaf(w0, bfh(u0), a1);
    }
    a0 += b0 + c0 + d0;
    a1 += b1v + c1 + d1;
}

// layer 1: h = elu(LN(gather + dinv^2*hw + b1)) + LN(proj)
__global__ __launch_bounds__(256) void gfuse1_k(
    const unsigned* __restrict__ hw, const unsigned* __restrict__ proj,
    const int* __restrict__ rowptr, const int2* __restrict__ csr,
    const float* __restrict__ dinv,
    const float* __restrict__ b1, const float* __restrict__ g1, const float* __restrict__ be1,
    const float* __restrict__ rg, const float* __restrict__ rbe,
    unsigned* __restrict__ hout, int n)
{
    int row = blockIdx.x * 4 + (threadIdx.x >> 6);
    if (row >= n) return;
    int lane = threadIdx.x & 63;
    float a0, a1;
    gather_row(hw, csr, rowptr[row], rowptr[row + 1], lane, a0, a1);
    long long off = (long long)row * 64;
    float di = dinv[row], sl = di * di;
    unsigned us = hw[off + lane];
    float2 bv  = *(const float2*)(b1 + 2 * lane);
    float2 gv  = *(const float2*)(g1 + 2 * lane);
    float2 bev = *(const float2*)(be1 + 2 * lane);
    float2 rgv = *(const float2*)(rg + 2 * lane);
    float2 rbv = *(const float2*)(rbe + 2 * lane);
    float v0 = a0 + sl * bfl(us) + bv.x;
    float v1 = a1 + sl * bfh(us) + bv.y;
    float o0, o1; ln_pair(v0, v1, o0, o1);
    float t0 = elu(o0 * gv.x + bev.x);
    float t1 = elu(o1 * gv.y + bev.y);
    unsigned up = proj[off + lane];
    float q0, q1; ln_pair(bfl(up), bfh(up), q0, q1);
    hout[off + lane] = pack_bf2(t0 + q0 * rgv.x + rbv.x, t1 + q1 * rgv.y + rbv.y);
}

// layer 2: h2 = elu(LN(gather + dinv^2*hw + b2)) + hprev
__global__ __launch_bounds__(256) void gfuse2_k(
    const unsigned* __restrict__ hw, const unsigned* __restrict__ hprev,
    const int* __restrict__ rowptr, const int2* __restrict__ csr,
    const float* __restrict__ dinv,
    const float* __restrict__ b2, const float* __restrict__ g2, const float* __restrict__ be2,
    unsigned* __restrict__ h2, int n)
{
    int row = blockIdx.x * 4 + (threadIdx.x >> 6);
    if (row >= n) return;
    int lane = threadIdx.x & 63;
    float a0, a1;
    gather_row(hw, csr, rowptr[row], rowptr[row + 1], lane, a0, a1);
    long long off = (long long)row * 64;
    float di = dinv[row], sl = di * di;
    unsigned us = hw[off + lane];
    float2 bv  = *(const float2*)(b2 + 2 * lane);
    float2 gv  = *(const float2*)(g2 + 2 * lane);
    float2 bev = *(const float2*)(be2 + 2 * lane);
    float v0 = a0 + sl * bfl(us) + bv.x;
    float v1 = a1 + sl * bfh(us) + bv.y;
    float o0, o1; ln_pair(v0, v1, o0, o1);
    float t0 = elu(o0 * gv.x + bev.x);
    float t1 = elu(o1 * gv.y + bev.y);
    unsigned uh = hprev[off + lane];
    h2[off + lane] = pack_bf2(t0 + bfl(uh), t1 + bfh(uh));
}

// ---------- LN + ELU on z (bf16) ----------
__global__ __launch_bounds__(256) void ln_elu_k(
    const unsigned* __restrict__ in, const float* __restrict__ g, const float* __restrict__ be,
    unsigned* __restrict__ outp, int n)
{
    int row = blockIdx.x * 4 + (threadIdx.x >> 6);
    if (row >= n) return;
    int lane = threadIdx.x & 63;
    long long off = (long long)row * 64;
    unsigned u = in[off + lane];
    float o0, o1; ln_pair(bfl(u), bfh(u), o0, o1);
    float2 gv  = *(const float2*)(g + 2 * lane);
    float2 bev = *(const float2*)(be + 2 * lane);
    outp[off + lane] = pack_bf2(elu(o0 * gv.x + bev.x), elu(o1 * gv.y + bev.y));
}

// ---------- H = z @ mW2 + mb2, softmax K=16; one wave per row ----------
__global__ __launch_bounds__(256) void final_k(
    const unsigned* __restrict__ z, const float* __restrict__ mW2, const float* __restrict__ mb2,
    float* __restrict__ out, int n)
{
    int row = blockIdx.x * 4 + (threadIdx.x >> 6);
    if (row >= n) return;
    int lane = threadIdx.x & 63;
    int k = lane & 15, seg = lane >> 4;
    const unsigned* zr = z + (long long)row * 64 + seg * 16;
    float acc = 0.f;
    #pragma unroll
    for (int jj = 0; jj < 16; jj++) {
        unsigned u = zr[jj];
        int c = seg * 32 + 2 * jj;
        acc = fmaf(bfl(u), mW2[c * 16 + k], acc);
        acc = fmaf(bfh(u), mW2[(c + 1) * 16 + k], acc);
    }
    acc += __shfl_xor(acc, 32, 64);
    acc += __shfl_xor(acc, 16, 64);
    float hk = acc + mb2[k];
    float mx = hk;
    #pragma unroll
    for (int o = 8; o > 0; o >>= 1) mx = fmaxf(mx, __shfl_xor(mx, o, 64));
    float e = expf(hk - mx);
    float s = e;
    #pragma unroll
    for (int o = 8; o > 0; o >>= 1) s += __shfl_xor(s, o, 64);
    if (lane < 16) out[(long long)row * 16 + k] = e / s;
}

// ---------- launcher ----------
static inline size_t align16(size_t x) { return (x + 15) & ~(size_t)15; }

extern "C" void kernel_launch(void* const* d_in, const int* in_sizes, int n_in,
                              void* d_out, int out_size, void* d_ws, size_t ws_size,
                              hipStream_t stream)
{
    const float* x   = (const float*)d_in[0];
    const int*   ei  = (const int*)d_in[1];
    const float* W1  = (const float*)d_in[2];
    const float* b1  = (const float*)d_in[3];
    const float* g1  = (const float*)d_in[4];
    const float* be1 = (const float*)d_in[5];
    const float* W2  = (const float*)d_in[6];
    const float* b2  = (const float*)d_in[7];
    const float* g2  = (const float*)d_in[8];
    const float* be2 = (const float*)d_in[9];
    const float* rW  = (const float*)d_in[10];
    const float* rb  = (const float*)d_in[11];
    const float* rg  = (const float*)d_in[12];
    const float* rbe = (const float*)d_in[13];
    const float* mW1 = (const float*)d_in[14];
    const float* mb1 = (const float*)d_in[15];
    const float* mg  = (const float*)d_in[16];
    const float* mbe = (const float*)d_in[17];
    const float* mW2 = (const float*)d_in[18];
    const float* mb2 = (const float*)d_in[19];
    float* out = (float*)d_out;

    const int n = in_sizes[0] / 384;
    const int E = in_sizes[1] / 2;
    const int* src = ei;
    const int* dst = ei + E;

    char* w = (char*)d_ws;
    int* deg     = (int*)w;   w += align16((size_t)n * 4);
    int* rowptr  = (int*)w;   w += align16((size_t)(n + 1) * 4);
    int* cursor  = (int*)w;   w += align16((size_t)n * 4);
    float* dinv  = (float*)w; w += align16((size_t)n * 4);
    int2* csr    = (int2*)w;  w += align16((size_t)E * 8);
    unsigned short* hw1  = (unsigned short*)w; w += align16((size_t)n * DH * 2);
    unsigned short* proj = (unsigned short*)w; w += align16((size_t)n * DH * 2);
    unsigned short* hbuf = (unsigned short*)w; w += align16((size_t)n * DH * 2);
    unsigned short* Wp1 = (unsigned short*)w; w += align16((size_t)384 * DH * 2);
    unsigned short* Wpr = (unsigned short*)w; w += align16((size_t)384 * DH * 2);
    unsigned short* Wp2 = (unsigned short*)w; w += align16((size_t)128 * DH * 2);
    unsigned short* WpM = (unsigned short*)w; w += align16((size_t)128 * DH * 2);
    unsigned short* hw2  = hw1;   // free after gfuse1
    unsigned short* h2   = proj;  // free after gfuse1
    unsigned short* zraw = hbuf;  // free after gfuse2
    unsigned short* zbuf = hw1;   // free after gfuse2

    int gE = (E + 255) / 256;
    int gN = (n + 255) / 256;
    int gG = (n + 63) / 64;
    int gRow4 = (n + 3) / 4;

    // CSR build
    zero_int_k<<<gN, 256, 0, stream>>>(deg, n);
    deg_count_k<<<gE, 256, 0, stream>>>(dst, deg, E);
    dinv_k<<<gN, 256, 0, stream>>>(deg, dinv, n);
    scan_k<<<1, 1024, 0, stream>>>(deg, rowptr, cursor, n);
    fill_k<<<gE, 256, 0, stream>>>(src, dst, dinv, cursor, csr, E);

    // weight repack to bf16 fragment panels
    repack_w_k<<<(384 * DH + 255) / 256, 256, 0, stream>>>(W1, Wp1, 384);
    repack_w_k<<<(384 * DH + 255) / 256, 256, 0, stream>>>(rW, Wpr, 384);
    repack_w_k<<<(128 * DH + 255) / 256, 256, 0, stream>>>(W2, Wp2, 128);
    repack_w_k<<<(128 * DH + 255) / 256, 256, 0, stream>>>(mW1, WpM, 128);

    // layer 1
    mfma_gemm<384, true, true><<<gG, 256, 0, stream>>>(x, Wp1, nullptr, Wpr, rb, hw1, proj, n);
    gfuse1_k<<<gRow4, 256, 0, stream>>>((unsigned*)hw1, (unsigned*)proj, rowptr, csr, dinv,
                                        b1, g1, be1, rg, rbe, (unsigned*)hbuf, n);

    // layer 2
    mfma_gemm<128, false, false><<<gG, 256, 0, stream>>>(hbuf, Wp2, nullptr, nullptr, nullptr, hw2, nullptr, n);
    gfuse2_k<<<gRow4, 256, 0, stream>>>((unsigned*)hw2, (unsigned*)hbuf, rowptr, csr, dinv,
                                        b2, g2, be2, (unsigned*)h2, n);

    // MLP head + softmax
    mfma_gemm<128, false, false><<<gG, 256, 0, stream>>>(h2, WpM, mb1, nullptr, nullptr, zraw, nullptr, n);
    ln_elu_k<<<gRow4, 256, 0, stream>>>((unsigned*)zraw, mg, mbe, (unsigned*)zbuf, n);
    final_k<<<gRow4, 256, 0, stream>>>((unsigned*)zbuf, mW2, mb2, out, n);
}

// Round 5
// 449.414 us; speedup vs baseline: 2.6793x; 1.0653x over previous
//
#include <hip/hip_runtime.h>

#define DH 128

typedef __attribute__((ext_vector_type(8))) short short8;
typedef __attribute__((ext_vector_type(4))) float f32x4;

// ---------- helpers ----------
__device__ __forceinline__ float wave_sum(float v) {
    #pragma unroll
    for (int o = 32; o > 0; o >>= 1) v += __shfl_xor(v, o, 64);
    return v;
}

__device__ __forceinline__ void ln_pair(float v0, float v1, float& o0, float& o1) {
    float m = wave_sum(v0 + v1) * (1.f / 128.f);
    float d0 = v0 - m, d1 = v1 - m;
    float var = wave_sum(d0 * d0 + d1 * d1) * (1.f / 128.f);
    float inv = rsqrtf(var + 1e-5f);
    o0 = d0 * inv; o1 = d1 * inv;
}

__device__ __forceinline__ float elu(float x) { return x > 0.f ? x : expm1f(x); }

// fp32 -> bf16 round-to-nearest-even
__device__ __forceinline__ unsigned short f2bf(float f) {
    unsigned u = __float_as_uint(f);
    u += 0x7fffu + ((u >> 16) & 1u);
    return (unsigned short)(u >> 16);
}
__device__ __forceinline__ float bfl(unsigned u) { return __uint_as_float(u << 16); }
__device__ __forceinline__ float bfh(unsigned u) { return __uint_as_float(u & 0xffff0000u); }
__device__ __forceinline__ unsigned pack_bf2(float a, float b) {
    return (unsigned)f2bf(a) | ((unsigned)f2bf(b) << 16);
}
__device__ __forceinline__ short8 cvt8(float4 v0, float4 v1) {
    short8 o;
    o[0] = (short)f2bf(v0.x); o[1] = (short)f2bf(v0.y);
    o[2] = (short)f2bf(v0.z); o[3] = (short)f2bf(v0.w);
    o[4] = (short)f2bf(v1.x); o[5] = (short)f2bf(v1.y);
    o[6] = (short)f2bf(v1.z); o[7] = (short)f2bf(v1.w);
    return o;
}

// ---------- utility kernels ----------
__global__ void zero_int_k(int* __restrict__ p, int n) {
    int i = blockIdx.x * 256 + threadIdx.x;
    if (i < n) p[i] = 0;
}

__global__ void deg_count_k(const int* __restrict__ dst, int* __restrict__ deg, int E) {
    int e = blockIdx.x * 256 + threadIdx.x;
    if (e < E) atomicAdd(&deg[dst[e]], 1);
}

__global__ void dinv_k(const int* __restrict__ deg, float* __restrict__ dinv, int n) {
    int i = blockIdx.x * 256 + threadIdx.x;
    if (i < n) dinv[i] = rsqrtf((float)(deg[i] + 1));  // +1 self-loop
}

// ---------- parallel exclusive scan (3 kernels) ----------
__global__ __launch_bounds__(1024) void scan_part_k(const int* __restrict__ deg,
                                                    int* __restrict__ rowptr,
                                                    int* __restrict__ bsum, int n)
{
    __shared__ int wsum[16];
    const int tid = threadIdx.x, lane = tid & 63, wid = tid >> 6;
    int i = blockIdx.x * 1024 + tid;
    int v = (i < n) ? deg[i] : 0;
    int s = v;
    #pragma unroll
    for (int o = 1; o < 64; o <<= 1) {
        int t = __shfl_up(s, o, 64);
        if (lane >= o) s += t;
    }
    if (lane == 63) wsum[wid] = s;
    __syncthreads();
    if (tid < 16) {
        int ws = wsum[tid];
        #pragma unroll
        for (int o = 1; o < 16; o <<= 1) {
            int t = __shfl_up(ws, o, 64);
            if (tid >= o) ws += t;
        }
        wsum[tid] = ws;
    }
    __syncthreads();
    int excl = (wid ? wsum[wid - 1] : 0) + s - v;
    if (i < n) rowptr[i] = excl;
    if (tid == 0) bsum[blockIdx.x] = wsum[15];
}

// single wave scans block sums (nb <= a few hundred), writes rowptr[n]=total
__global__ void scan_top_k(int* __restrict__ bsum, int* __restrict__ rowptr_n, int nb) {
    int lane = threadIdx.x;  // blockDim = 64
    int carry = 0;
    for (int base = 0; base < nb; base += 64) {
        int i = base + lane;
        int v = (i < nb) ? bsum[i] : 0;
        int s = v;
        #pragma unroll
        for (int o = 1; o < 64; o <<= 1) {
            int t = __shfl_up(s, o, 64);
            if (lane >= o) s += t;
        }
        if (i < nb) bsum[i] = carry + s - v;
        carry += __shfl(s, 63, 64);
    }
    if (lane == 0) *rowptr_n = carry;
}

__global__ void scan_add_k(const int* __restrict__ bsum, int* __restrict__ rowptr,
                           int* __restrict__ cursor, int n)
{
    int i = blockIdx.x * 256 + threadIdx.x;
    if (i < n) {
        int v = rowptr[i] + bsum[i >> 10];
        rowptr[i] = v;
        cursor[i] = v;
    }
}

__global__ void fill_k(const int* __restrict__ src, const int* __restrict__ dst,
                       const float* __restrict__ dinv, int* __restrict__ cursor,
                       int2* __restrict__ csr, int E)
{
    int e = blockIdx.x * 256 + threadIdx.x;
    if (e < E) {
        int s = src[e], d = dst[e];
        float w = dinv[s] * dinv[d];
        int p = atomicAdd(&cursor[d], 1);
        csr[p] = make_int2(s, __float_as_int(w));
    }
}

// repack W [K x 128] fp32 -> Wp[kb][n][32] bf16 (fragment-ordered panels)
__global__ void repack_w_k(const float* __restrict__ W, unsigned short* __restrict__ Wp, int K) {
    int idx = blockIdx.x * 256 + threadIdx.x;
    if (idx >= K * DH) return;
    int kb  = idx / (DH * 32);
    int rem = idx - kb * (DH * 32);
    int nn  = rem >> 5;
    int ki  = rem & 31;
    Wp[idx] = f2bf(W[(kb * 32 + ki) * DH + nn]);
}

// ---------- LDS-free MFMA GEMM ----------
// grid (ceil(n/128), 2). Wave w of block: rows bx*128 + w*32 .. +32, cols by*64 .. +64.
// A/B fragments loaded straight global->VGPR (B panels are fragment-ordered, L2-hot).
// Double-buffered prefetch, no barriers, no LDS.
template<int K, bool DUAL, bool AF32>
__global__ __launch_bounds__(256) void mfma_gemm(
    const void* __restrict__ Av,
    const unsigned short* __restrict__ Bp1, const float* __restrict__ ba,
    const unsigned short* __restrict__ Bp2, const float* __restrict__ bb,
    unsigned short* __restrict__ outa, unsigned short* __restrict__ outb, int n)
{
    constexpr int NKB = K / 32;
    const int tid = threadIdx.x;
    const int wid = tid >> 6, lane = tid & 63;
    const int m16 = lane & 15, q = lane >> 4;
    const long long rb0 = (long long)blockIdx.x * 128 + wid * 32;
    const int colb = blockIdx.y * 64;

    long long r0 = rb0 + m16;      if (r0 > (long long)n - 1) r0 = n - 1;
    long long r1 = rb0 + 16 + m16; if (r1 > (long long)n - 1) r1 = n - 1;

    const float* Af = (const float*)Av;
    const unsigned short* Ah = (const unsigned short*)Av;

    f32x4 acc1[2][4], acc2[2][4];
    const f32x4 zero = {0.f, 0.f, 0.f, 0.f};
    #pragma unroll
    for (int i = 0; i < 2; i++)
        #pragma unroll
        for (int j = 0; j < 4; j++) { acc1[i][j] = zero; if constexpr (DUAL) acc2[i][j] = zero; }

    float4 ra[2][2][2];   // [buf][mi][half] raw fp32
    short8 ha[2][2];      // [buf][mi] bf16
    short8 pb1[2][4], pb2[2][4];

    auto fetch = [&](int kb, int buf) {
        if constexpr (AF32) {
            const float* p0 = Af + r0 * K + kb * 32 + q * 8;
            const float* p1 = Af + r1 * K + kb * 32 + q * 8;
            ra[buf][0][0] = *(const float4*)p0;  ra[buf][0][1] = *(const float4*)(p0 + 4);
            ra[buf][1][0] = *(const float4*)p1;  ra[buf][1][1] = *(const float4*)(p1 + 4);
        } else {
            ha[buf][0] = *(const short8*)(Ah + r0 * K + kb * 32 + q * 8);
            ha[buf][1] = *(const short8*)(Ah + r1 * K + kb * 32 + q * 8);
        }
        #pragma unroll
        for (int nj = 0; nj < 4; ++nj) {
            long long boff = ((long long)kb * 128 + colb + nj * 16 + m16) * 32 + q * 8;
            pb1[buf][nj] = *(const short8*)(Bp1 + boff);
            if constexpr (DUAL) pb2[buf][nj] = *(const short8*)(Bp2 + boff);
        }
    };

    fetch(0, 0);
    #pragma unroll
    for (int kb = 0; kb < NKB; ++kb) {
        const int cur = kb & 1, nxt = cur ^ 1;
        if (kb + 1 < NKB) fetch(kb + 1, nxt);
        short8 af[2];
        if constexpr (AF32) {
            af[0] = cvt8(ra[cur][0][0], ra[cur][0][1]);
            af[1] = cvt8(ra[cur][1][0], ra[cur][1][1]);
        } else {
            af[0] = ha[cur][0];
            af[1] = ha[cur][1];
        }
        #pragma unroll
        for (int mi = 0; mi < 2; ++mi)
            #pragma unroll
            for (int nj = 0; nj < 4; ++nj) {
                acc1[mi][nj] = __builtin_amdgcn_mfma_f32_16x16x32_bf16(af[mi], pb1[cur][nj], acc1[mi][nj], 0, 0, 0);
                if constexpr (DUAL)
                    acc2[mi][nj] = __builtin_amdgcn_mfma_f32_16x16x32_bf16(af[mi], pb2[cur][nj], acc2[mi][nj], 0, 0, 0);
            }
    }

    // epilogue: C/D layout col=lane&15, row=(lane>>4)*4+reg; bf16 stores
    #pragma unroll
    for (int nj = 0; nj < 4; ++nj) {
        int col = colb + nj * 16 + m16;
        float bav = ba ? ba[col] : 0.f;
        float bbv = 0.f;
        if constexpr (DUAL) bbv = bb ? bb[col] : 0.f;
        #pragma unroll
        for (int mi = 0; mi < 2; ++mi) {
            long long row0 = rb0 + mi * 16 + q * 4;
            #pragma unroll
            for (int r = 0; r < 4; ++r) {
                long long rr = row0 + r;
                if (rr < n) {
                    outa[rr * DH + col] = f2bf(acc1[mi][nj][r] + bav);
                    if constexpr (DUAL) outb[rr * DH + col] = f2bf(acc2[mi][nj][r] + bbv);
                }
            }
        }
    }
}

// ---------- CSR gather (bf16 rows), one wave per row, 8 loads in flight ----------
__device__ __forceinline__ void gather_row(
    const unsigned* __restrict__ hw, const int2* __restrict__ csr,
    int beg, int end, int lane, float& o0, float& o1)
{
    float a0 = 0.f, a1 = 0.f, b0 = 0.f, b1 = 0.f;
    float c0 = 0.f, c1 = 0.f, d0 = 0.f, d1 = 0.f;
    int p = beg;
    for (; p + 7 < end; p += 8) {
        int2 e0 = csr[p],     e1 = csr[p + 1], e2 = csr[p + 2], e3 = csr[p + 3];
        int2 e4 = csr[p + 4], e5 = csr[p + 5], e6 = csr[p + 6], e7 = csr[p + 7];
        unsigned u0 = hw[(long long)e0.x * 64 + lane];
        unsigned u1 = hw[(long long)e1.x * 64 + lane];
        unsigned u2 = hw[(long long)e2.x * 64 + lane];
        unsigned u3 = hw[(long long)e3.x * 64 + lane];
        unsigned u4 = hw[(long long)e4.x * 64 + lane];
        unsigned u5 = hw[(long long)e5.x * 64 + lane];
        unsigned u6 = hw[(long long)e6.x * 64 + lane];
        unsigned u7 = hw[(long long)e7.x * 64 + lane];
        float w0 = __int_as_float(e0.y), w1 = __int_as_float(e1.y);
        float w2 = __int_as_float(e2.y), w3 = __int_as_float(e3.y);
        float w4 = __int_as_float(e4.y), w5 = __int_as_float(e5.y);
        float w6 = __int_as_float(e6.y), w7 = __int_as_float(e7.y);
        a0 = fmaf(w0, bfl(u0), a0);  a1 = fmaf(w0, bfh(u0), a1);
        b0 = fmaf(w1, bfl(u1), b0);  b1 = fmaf(w1, bfh(u1), b1);
        c0 = fmaf(w2, bfl(u2), c0);  c1 = fmaf(w2, bfh(u2), c1);
        d0 = fmaf(w3, bfl(u3), d0);  d1 = fmaf(w3, bfh(u3), d1);
        a0 = fmaf(w4, bfl(u4), a0);  a1 = fmaf(w4, bfh(u4), a1);
        b0 = fmaf(w5, bfl(u5), b0);  b1 = fmaf(w5, bfh(u5), b1);
        c0 = fmaf(w6, bfl(u6), c0);  c1 = fmaf(w6, bfh(u6), c1);
        d0 = fmaf(w7, bfl(u7), d0);  d1 = fmaf(w7, bfh(u7), d1);
    }
    for (; p + 3 < end; p += 4) {
        int2 e0 = csr[p], e1 = csr[p + 1], e2 = csr[p + 2], e3 = csr[p + 3];
        unsigned u0 = hw[(long long)e0.x * 64 + lane];
        unsigned u1 = hw[(long long)e1.x * 64 + lane];
        unsigned u2 = hw[(long long)e2.x * 64 + lane];
        unsigned u3 = hw[(long long)e3.x * 64 + lane];
        float w0 = __int_as_float(e0.y), w1 = __int_as_float(e1.y);
        float w2 = __int_as_float(e2.y), w3 = __int_as_float(e3.y);
        a0 = fmaf(w0, bfl(u0), a0);  a1 = fmaf(w0, bfh(u0), a1);
        b0 = fmaf(w1, bfl(u1), b0);  b1 = fmaf(w1, bfh(u1), b1);
        c0 = fmaf(w2, bfl(u2), c0);  c1 = fmaf(w2, bfh(u2), c1);
        d0 = fmaf(w3, bfl(u3), d0);  d1 = fmaf(w3, bfh(u3), d1);
    }
    for (; p < end; ++p) {
        int2 e0 = csr[p];
        unsigned u0 = hw[(long long)e0.x * 64 + lane];
        float w0 = __int_as_float(e0.y);
        a0 = fmaf(w0, bfl(u0), a0);
        a1 = fmaf(w0, bfh(u0), a1);
    }
    o0 = (a0 + b0) + (c0 + d0);
    o1 = (a1 + b1) + (c1 + d1);
}

// layer 1: h = elu(LN(gather + dinv^2*hw + b1)) + LN(proj)
__global__ __launch_bounds__(256) void gfuse1_k(
    const unsigned* __restrict__ hw, const unsigned* __restrict__ proj,
    const int* __restrict__ rowptr, const int2* __restrict__ csr,
    const float* __restrict__ dinv,
    const float* __restrict__ b1, const float* __restrict__ g1, const float* __restrict__ be1,
    const float* __restrict__ rg, const float* __restrict__ rbe,
    unsigned* __restrict__ hout, int n)
{
    int row = blockIdx.x * 4 + (threadIdx.x >> 6);
    if (row >= n) return;
    int lane = threadIdx.x & 63;
    float a0, a1;
    gather_row(hw, csr, rowptr[row], rowptr[row + 1], lane, a0, a1);
    long long off = (long long)row * 64;
    float di = dinv[row], sl = di * di;
    unsigned us = hw[off + lane];
    float2 bv  = *(const float2*)(b1 + 2 * lane);
    float2 gv  = *(const float2*)(g1 + 2 * lane);
    float2 bev = *(const float2*)(be1 + 2 * lane);
    float2 rgv = *(const float2*)(rg + 2 * lane);
    float2 rbv = *(const float2*)(rbe + 2 * lane);
    float v0 = a0 + sl * bfl(us) + bv.x;
    float v1 = a1 + sl * bfh(us) + bv.y;
    float o0, o1; ln_pair(v0, v1, o0, o1);
    float t0 = elu(o0 * gv.x + bev.x);
    float t1 = elu(o1 * gv.y + bev.y);
    unsigned up = proj[off + lane];
    float q0, q1; ln_pair(bfl(up), bfh(up), q0, q1);
    hout[off + lane] = pack_bf2(t0 + q0 * rgv.x + rbv.x, t1 + q1 * rgv.y + rbv.y);
}

// layer 2: h2 = elu(LN(gather + dinv^2*hw + b2)) + hprev
__global__ __launch_bounds__(256) void gfuse2_k(
    const unsigned* __restrict__ hw, const unsigned* __restrict__ hprev,
    const int* __restrict__ rowptr, const int2* __restrict__ csr,
    const float* __restrict__ dinv,
    const float* __restrict__ b2, const float* __restrict__ g2, const float* __restrict__ be2,
    unsigned* __restrict__ h2, int n)
{
    int row = blockIdx.x * 4 + (threadIdx.x >> 6);
    if (row >= n) return;
    int lane = threadIdx.x & 63;
    float a0, a1;
    gather_row(hw, csr, rowptr[row], rowptr[row + 1], lane, a0, a1);
    long long off = (long long)row * 64;
    float di = dinv[row], sl = di * di;
    unsigned us = hw[off + lane];
    float2 bv  = *(const float2*)(b2 + 2 * lane);
    float2 gv  = *(const float2*)(g2 + 2 * lane);
    float2 bev = *(const float2*)(be2 + 2 * lane);
    float v0 = a0 + sl * bfl(us) + bv.x;
    float v1 = a1 + sl * bfh(us) + bv.y;
    float o0, o1; ln_pair(v0, v1, o0, o1);
    float t0 = elu(o0 * gv.x + bev.x);
    float t1 = elu(o1 * gv.y + bev.y);
    unsigned uh = hprev[off + lane];
    h2[off + lane] = pack_bf2(t0 + bfl(uh), t1 + bfh(uh));
}

// ---------- head: LN+ELU on zraw, z @ mW2 + mb2, softmax K=16 (fused) ----------
__global__ __launch_bounds__(256) void head_k(
    const unsigned* __restrict__ zraw, const float* __restrict__ g, const float* __restrict__ be,
    const float* __restrict__ mW2, const float* __restrict__ mb2,
    float* __restrict__ out, int n)
{
    int row = blockIdx.x * 4 + (threadIdx.x >> 6);
    if (row >= n) return;
    int lane = threadIdx.x & 63;
    unsigned u = zraw[(long long)row * 64 + lane];
    float o0, o1; ln_pair(bfl(u), bfh(u), o0, o1);
    float2 gv  = *(const float2*)(g + 2 * lane);
    float2 bev = *(const float2*)(be + 2 * lane);
    float z0 = elu(o0 * gv.x + bev.x);   // col 2*lane
    float z1 = elu(o1 * gv.y + bev.y);   // col 2*lane+1
    int k = lane & 15, seg = lane >> 4;
    float acc = 0.f;
    #pragma unroll
    for (int t = 0; t < 16; ++t) {
        int srcl = seg * 16 + t;                // lane holding cols seg*32+2t, +2t+1
        float zz0 = __shfl(z0, srcl, 64);
        float zz1 = __shfl(z1, srcl, 64);
        int c = seg * 32 + 2 * t;
        acc = fmaf(zz0, mW2[c * 16 + k], acc);
        acc = fmaf(zz1, mW2[(c + 1) * 16 + k], acc);
    }
    acc += __shfl_xor(acc, 32, 64);
    acc += __shfl_xor(acc, 16, 64);
    float hk = acc + mb2[k];
    float mx = hk;
    #pragma unroll
    for (int o = 8; o > 0; o >>= 1) mx = fmaxf(mx, __shfl_xor(mx, o, 64));
    float e = expf(hk - mx);
    float s = e;
    #pragma unroll
    for (int o = 8; o > 0; o >>= 1) s += __shfl_xor(s, o, 64);
    if (lane < 16) out[(long long)row * 16 + k] = e / s;
}

// ---------- launcher ----------
static inline size_t align16(size_t x) { return (x + 15) & ~(size_t)15; }

extern "C" void kernel_launch(void* const* d_in, const int* in_sizes, int n_in,
                              void* d_out, int out_size, void* d_ws, size_t ws_size,
                              hipStream_t stream)
{
    const float* x   = (const float*)d_in[0];
    const int*   ei  = (const int*)d_in[1];
    const float* W1  = (const float*)d_in[2];
    const float* b1  = (const float*)d_in[3];
    const float* g1  = (const float*)d_in[4];
    const float* be1 = (const float*)d_in[5];
    const float* W2  = (const float*)d_in[6];
    const float* b2  = (const float*)d_in[7];
    const float* g2  = (const float*)d_in[8];
    const float* be2 = (const float*)d_in[9];
    const float* rW  = (const float*)d_in[10];
    const float* rb  = (const float*)d_in[11];
    const float* rg  = (const float*)d_in[12];
    const float* rbe = (const float*)d_in[13];
    const float* mW1 = (const float*)d_in[14];
    const float* mb1 = (const float*)d_in[15];
    const float* mg  = (const float*)d_in[16];
    const float* mbe = (const float*)d_in[17];
    const float* mW2 = (const float*)d_in[18];
    const float* mb2 = (const float*)d_in[19];
    float* out = (float*)d_out;

    const int n = in_sizes[0] / 384;
    const int E = in_sizes[1] / 2;
    const int* src = ei;
    const int* dst = ei + E;

    char* w = (char*)d_ws;
    int* deg     = (int*)w;   w += align16((size_t)n * 4);
    int* rowptr  = (int*)w;   w += align16((size_t)(n + 1) * 4);
    int* cursor  = (int*)w;   w += align16((size_t)n * 4);
    float* dinv  = (float*)w; w += align16((size_t)n * 4);
    int* bsum    = (int*)w;   w += align16((size_t)1024 * 4);
    int2* csr    = (int2*)w;  w += align16((size_t)E * 8);
    unsigned short* hw1  = (unsigned short*)w; w += align16((size_t)n * DH * 2);
    unsigned short* proj = (unsigned short*)w; w += align16((size_t)n * DH * 2);
    unsigned short* hbuf = (unsigned short*)w; w += align16((size_t)n * DH * 2);
    unsigned short* Wp1 = (unsigned short*)w; w += align16((size_t)384 * DH * 2);
    unsigned short* Wpr = (unsigned short*)w; w += align16((size_t)384 * DH * 2);
    unsigned short* Wp2 = (unsigned short*)w; w += align16((size_t)128 * DH * 2);
    unsigned short* WpM = (unsigned short*)w; w += align16((size_t)128 * DH * 2);
    unsigned short* hw2  = hw1;   // free after gfuse1
    unsigned short* h2   = proj;  // free after gfuse1
    unsigned short* zraw = hbuf;  // free after gfuse2

    int gE = (E + 255) / 256;
    int gN = (n + 255) / 256;
    int nb = (n + 1023) / 1024;
    dim3 gG((n + 127) / 128, 2);
    int gRow4 = (n + 3) / 4;

    // CSR build
    zero_int_k<<<gN, 256, 0, stream>>>(deg, n);
    deg_count_k<<<gE, 256, 0, stream>>>(dst, deg, E);
    dinv_k<<<gN, 256, 0, stream>>>(deg, dinv, n);
    scan_part_k<<<nb, 1024, 0, stream>>>(deg, rowptr, bsum, n);
    scan_top_k<<<1, 64, 0, stream>>>(bsum, rowptr + n, nb);
    scan_add_k<<<gN, 256, 0, stream>>>(bsum, rowptr, cursor, n);
    fill_k<<<gE, 256, 0, stream>>>(src, dst, dinv, cursor, csr, E);

    // weight repack to bf16 fragment panels
    repack_w_k<<<(384 * DH + 255) / 256, 256, 0, stream>>>(W1, Wp1, 384);
    repack_w_k<<<(384 * DH + 255) / 256, 256, 0, stream>>>(rW, Wpr, 384);
    repack_w_k<<<(128 * DH + 255) / 256, 256, 0, stream>>>(W2, Wp2, 128);
    repack_w_k<<<(128 * DH + 255) / 256, 256, 0, stream>>>(mW1, WpM, 128);

    // layer 1
    mfma_gemm<384, true, true><<<gG, 256, 0, stream>>>(x, Wp1, nullptr, Wpr, rb, hw1, proj, n);
    gfuse1_k<<<gRow4, 256, 0, stream>>>((unsigned*)hw1, (unsigned*)proj, rowptr, csr, dinv,
                                        b1, g1, be1, rg, rbe, (unsigned*)hbuf, n);

    // layer 2
    mfma_gemm<128, false, false><<<gG, 256, 0, stream>>>(hbuf, Wp2, nullptr, nullptr, nullptr, hw2, nullptr, n);
    gfuse2_k<<<gRow4, 256, 0, stream>>>((unsigned*)hw2, (unsigned*)hbuf, rowptr, csr, dinv,
                                        b2, g2, be2, (unsigned*)h2, n);

    // MLP head + softmax
    mfma_gemm<128, false, false><<<gG, 256, 0, stream>>>(h2, WpM, mb1, nullptr, nullptr, zraw, nullptr, n);
    head_k<<<gRow4, 256, 0, stream>>>((unsigned*)zraw, mg, mbe, mW2, mb2, out, n);
}